// Round 12
// baseline (2902.257 us; speedup 1.0000x reference)
//
#include <hip/hip_runtime.h>
#include <cstdint>

// SelfMatchingLayer: B=32, L=512, H=256, fp32.
// R10 (4th submit; broker timeouts r9/r10/r11, never ran): k7 MFMA core
//      (validated by R9: passed, scratch gone, MfmaUtil>0) with
//      restructured schedule. R9's 4730cy/step came from: 2 full-drain
//      barriers (__syncthreads waits vmcnt(0) -> out-store acks + load
//      returns on critical path), serial nt-chains (6x8 dependent MFMAs),
//      gh LDS round-trip. R10: (a) gate-split cols -> GRU reads D regs
//      directly, gh array + one barrier deleted; (b) h ping-pong kills the
//      WAR race -> ONE raw s_barrier/step with lgkmcnt(0) + counted
//      vmcnt(19) (stores never waited); (c) kt-outer MFMA -> 6 independent
//      chains; (d) h2T [kt][lq][lr] layout -> Af ds_read_b128 lane-
//      consecutive, conflict-free; (e) gi ring-3, prefetch depth 2.
//      k1-k6 unchanged.

#define LL 512
#define HH 256

typedef _Float16 half2_t __attribute__((ext_vector_type(2)));
typedef _Float16 f16x8   __attribute__((ext_vector_type(8)));
typedef float    f32x4   __attribute__((ext_vector_type(4)));

__device__ __forceinline__ float exp2f_fast(float x){
#if defined(__HIP_DEVICE_COMPILE__)
  return __builtin_amdgcn_exp2f(x);
#else
  return exp2f(x);
#endif
}
__device__ __forceinline__ float rcpf_fast(float x){
#if defined(__HIP_DEVICE_COMPILE__)
  return __builtin_amdgcn_rcpf(x);
#else
  return 1.0f/x;
#endif
}
__device__ __forceinline__ float tanh_fast(float x){
  float e = exp2f_fast(x * 2.885390081777927f);   // 2*log2(e)
  return 1.0f - 2.0f * rcpf_fast(1.0f + e);
}
__device__ __forceinline__ float sigmoid_fast(float x){
  return rcpf_fast(1.0f + exp2f_fast(x * -1.4426950408889634f));
}

#define SCALE_K2 2.885390081777927f   // 2*log2(e)

#if defined(__HIP_DEVICE_COMPILE__) && __has_builtin(__builtin_amdgcn_fdot2)
#define USE_FDOT2 1
#endif

__device__ __forceinline__ float dot2_acc(unsigned wb, unsigned hb, float a){
  half2_t wv = __builtin_bit_cast(half2_t, wb);
  half2_t hv = __builtin_bit_cast(half2_t, hb);
#ifdef USE_FDOT2
  return __builtin_amdgcn_fdot2(wv, hv, a, false);
#else
  return a + (float)wv.x*(float)hv.x + (float)wv.y*(float)hv.y;
#endif
}

__device__ __forceinline__ unsigned pack2h(float a, float b){
  half2_t h = { (_Float16)a, (_Float16)b };
  return __builtin_bit_cast(unsigned, h);
}
__device__ __forceinline__ f16x8 pack8(float4 a, float4 b){
  f16x8 v;
  v[0]=(_Float16)a.x; v[1]=(_Float16)a.y; v[2]=(_Float16)a.z; v[3]=(_Float16)a.w;
  v[4]=(_Float16)b.x; v[5]=(_Float16)b.y; v[6]=(_Float16)b.z; v[7]=(_Float16)b.w;
  return v;
}
__device__ __forceinline__ void gload_lds16(const float* src, float* dst){
  __builtin_amdgcn_global_load_lds(
      (const __attribute__((address_space(1))) void*)src,
      (__attribute__((address_space(3))) void*)dst,
      16, 0, 0);
}

// ==== fp32 128x128-tile GEMM helpers (k1 only) ===========================
__device__ __forceinline__ void stage_t128(float* Ls, const float* g, int ldg){
  int tid = threadIdx.x;
  int r = tid >> 4, kq = (tid & 15) * 4;
  #pragma unroll
  for (int it = 0; it < 8; it++){
    int rr = r + 16*it;
    float4 v = *(const float4*)(g + (size_t)rr*ldg + kq);
    Ls[(kq+0)*132 + rr] = v.x;
    Ls[(kq+1)*132 + rr] = v.y;
    Ls[(kq+2)*132 + rr] = v.z;
    Ls[(kq+3)*132 + rr] = v.w;
  }
}
__device__ __forceinline__ void rg_inner128(const float* Xs, const float* Ws,
                                            float (&acc)[8][8], int rg, int cg){
  #pragma unroll 2
  for (int k = 0; k < 64; k++){
    const float* xr = Xs + k*132;
    const float* wr = Ws + k*132;
    float4 x0 = *(const float4*)(xr + rg*4);
    float4 x1 = *(const float4*)(xr + 64 + rg*4);
    float4 w0 = *(const float4*)(wr + cg*4);
    float4 w1 = *(const float4*)(wr + 64 + cg*4);
    float xv[8] = {x0.x,x0.y,x0.z,x0.w, x1.x,x1.y,x1.z,x1.w};
    float wv[8] = {w0.x,w0.y,w0.z,w0.w, w1.x,w1.y,w1.z,w1.w};
    #pragma unroll
    for (int i=0;i<8;i++)
      #pragma unroll
      for (int j=0;j<8;j++)
        acc[i][j] = fmaf(xv[i], wv[j], acc[i][j]);
  }
}
#define ROW_OF(i, rg) ((rg)*4 + ((i)&3) + ((i)>>2)*64)
#define COL_OF(j, cg) ((cg)*4 + ((j)&3) + ((j)>>2)*64)

// ==== packed-fp16 128x128-tile GEMM helpers (k4/k5/k6) ===================
__device__ __forceinline__ void stage_t128_h(unsigned* Ls, const float* g, int ldg){
  int tid = threadIdx.x;
  int r = tid >> 4, kq = (tid & 15) * 4;
  #pragma unroll
  for (int it = 0; it < 8; it++){
    int rr = r + 16*it;
    float4 v = *(const float4*)(g + (size_t)rr*ldg + kq);
    Ls[((kq>>1)+0)*132 + rr] = pack2h(v.x, v.y);
    Ls[((kq>>1)+1)*132 + rr] = pack2h(v.z, v.w);
  }
}
__device__ __forceinline__ void stage_dpack_h(unsigned* Ls, const float* g, int ldg){
  int tid = threadIdx.x;
  int kr = tid >> 5, eq = (tid & 31) * 4;
  #pragma unroll
  for (int it = 0; it < 4; it++){
    int lp = kr + 8*it;
    float4 a = *(const float4*)(g + (size_t)(2*lp  )*ldg + eq);
    float4 b = *(const float4*)(g + (size_t)(2*lp+1)*ldg + eq);
    uint4 o;
    o.x = pack2h(a.x, b.x);
    o.y = pack2h(a.y, b.y);
    o.z = pack2h(a.z, b.z);
    o.w = pack2h(a.w, b.w);
    *(uint4*)(Ls + lp*132 + eq) = o;
  }
}
__device__ __forceinline__ void rg_inner128_h(const unsigned* Xs, const unsigned* Ws,
                                              float (&acc)[8][8], int rg, int cg){
  #pragma unroll 2
  for (int kp = 0; kp < 32; kp++){
    const unsigned* xr = Xs + kp*132;
    const unsigned* wr = Ws + kp*132;
    uint4 x0 = *(const uint4*)(xr + rg*4);
    uint4 x1 = *(const uint4*)(xr + 64 + rg*4);
    uint4 w0 = *(const uint4*)(wr + cg*4);
    uint4 w1 = *(const uint4*)(wr + 64 + cg*4);
    unsigned xv[8] = {x0.x,x0.y,x0.z,x0.w, x1.x,x1.y,x1.z,x1.w};
    unsigned wv[8] = {w0.x,w0.y,w0.z,w0.w, w1.x,w1.y,w1.z,w1.w};
    #pragma unroll
    for (int i=0;i<8;i++)
      #pragma unroll
      for (int j=0;j<8;j++)
        acc[i][j] = dot2_acc(xv[i], wv[j], acc[i][j]);
  }
}

// ---------------- K1: HQ' = SC*(P@wq^T+bq) ; PP' = SC*(P@wp^T+bp) --------
__global__ __launch_bounds__(256) void k1_hq_pp(
    const float* __restrict__ P,
    const float* __restrict__ wq_w, const float* __restrict__ wq_b,
    const float* __restrict__ wp_w, const float* __restrict__ wp_b,
    float* __restrict__ HQ, float* __restrict__ PP)
{
  __shared__ __align__(16) float Xs[64*132];
  __shared__ __align__(16) float Ws[64*132];
  int rt = blockIdx.x, ct = blockIdx.y;
  const float* W  = (ct < 2) ? wq_w : wp_w;
  const float* Bv = (ct < 2) ? wq_b : wp_b;
  float* O = (ct < 2) ? HQ : PP;
  int c0 = (ct & 1) * 128, r0 = rt * 128;
  int tid = threadIdx.x, rg = tid & 15, cg = tid >> 4;
  float acc[8][8];
  #pragma unroll
  for (int i=0;i<8;i++)
    #pragma unroll
    for (int j=0;j<8;j++) acc[i][j]=0.f;
  for (int kc = 0; kc < 4; kc++){
    __syncthreads();
    stage_t128(Xs, P + (size_t)r0*HH + kc*64, HH);
    stage_t128(Ws, W + (size_t)c0*HH + kc*64, HH);
    __syncthreads();
    rg_inner128(Xs, Ws, acc, rg, cg);
  }
  float bj[8];
  #pragma unroll
  for (int j=0;j<8;j++) bj[j] = Bv[c0 + COL_OF(j,cg)];
  #pragma unroll
  for (int i=0;i<8;i++){
    int r = r0 + ROW_OF(i,rg);
    #pragma unroll
    for (int j=0;j<8;j++)
      O[(size_t)r*HH + c0 + COL_OF(j,cg)] = SCALE_K2 * (acc[i][j] + bj[j]);
  }
}

// ---------------- K2: S_eff[b,t,l] = -2 * sum_h w_h / (1 + exp2(HQ'+PP')) -
__global__ __launch_bounds__(256) void k2_scores(
    const float* __restrict__ HQ, const float* __restrict__ PP,
    const float* __restrict__ ws_w, float* __restrict__ S)
{
  __shared__ float Hq_c[128*65];
  __shared__ float Pp_c[32*65];
  __shared__ float wsl[256];
  int tid = threadIdx.x;
  int b = blockIdx.y, t0 = blockIdx.x * 32;
  wsl[tid] = ws_w[tid];
  int tg = tid >> 6;
  int lg = tid & 63;
  for (int lc = 0; lc < 4; lc++){
    float acc[8][2];
    #pragma unroll
    for (int i=0;i<8;i++){ acc[i][0]=0.f; acc[i][1]=0.f; }
    for (int hc = 0; hc < 4; hc++){
      __syncthreads();
      {
        int r = tid >> 4, kq = (tid & 15) * 4;
        #pragma unroll
        for (int it=0; it<2; it++){
          int t = r + 16*it;
          float4 v = *(const float4*)(PP + ((size_t)b*LL + t0 + t)*HH + hc*64 + kq);
          float* d = Pp_c + t*65 + kq;
          d[0]=v.x; d[1]=v.y; d[2]=v.z; d[3]=v.w;
        }
      }
      {
        int r = tid >> 4, kq = (tid & 15) * 4;
        #pragma unroll
        for (int it=0; it<8; it++){
          int l = r + 16*it;
          float4 v = *(const float4*)(HQ + ((size_t)b*LL + lc*128 + l)*HH + hc*64 + kq);
          float* d = Hq_c + l*65 + kq;
          d[0]=v.x; d[1]=v.y; d[2]=v.z; d[3]=v.w;
        }
      }
      __syncthreads();
      #pragma unroll 2
      for (int h = 0; h < 64; h++){
        float w = wsl[hc*64 + h];
        float pp[8], hq[2];
        #pragma unroll
        for (int i=0;i<8;i++) pp[i] = Pp_c[(tg + 4*i)*65 + h];
        #pragma unroll
        for (int j=0;j<2;j++) hq[j] = Hq_c[(2*lg + j)*65 + h];
        #pragma unroll
        for (int i=0;i<8;i++)
          #pragma unroll
          for (int j=0;j<2;j++){
            float e = exp2f_fast(pp[i] + hq[j]);
            acc[i][j] = fmaf(w, rcpf_fast(1.0f + e), acc[i][j]);
          }
      }
    }
    #pragma unroll
    for (int i=0;i<8;i++)
      #pragma unroll
      for (int j=0;j<2;j++)
        S[((size_t)b*LL + t0 + tg + 4*i)*LL + lc*128 + 2*lg + j] = -2.0f*acc[i][j];
    __syncthreads();
  }
}

// ---------------- K3: softmax over l, in place; one wave per row ----------
__global__ __launch_bounds__(256) void k3_softmax(float* __restrict__ S)
{
  int wave = threadIdx.x >> 6, lane = threadIdx.x & 63;
  size_t row = (size_t)blockIdx.x*4 + wave;
  float* p = S + row*LL;
  float v[8];
  #pragma unroll
  for (int i=0;i<8;i++) v[i] = p[lane + 64*i];
  float m = v[0];
  #pragma unroll
  for (int i=1;i<8;i++) m = fmaxf(m, v[i]);
  #pragma unroll
  for (int off=32; off>=1; off>>=1) m = fmaxf(m, __shfl_xor(m, off, 64));
  float s = 0.f;
  #pragma unroll
  for (int i=0;i<8;i++){ v[i] = exp2f_fast((v[i]-m)*1.4426950408889634f); s += v[i]; }
  #pragma unroll
  for (int off=32; off>=1; off>>=1) s += __shfl_xor(s, off, 64);
  float inv = 1.0f / s;
  #pragma unroll
  for (int i=0;i<8;i++) p[lane + 64*i] = v[i]*inv;
}

// ---------------- K4: C[b,t,:] = attn[b,t,:] @ P[b,:,:] (fdot2) -----------
__global__ __launch_bounds__(256, 4) void k4_context(
    const float* __restrict__ S, const float* __restrict__ P, float* __restrict__ C)
{
  __shared__ __align__(16) unsigned As[32*132];
  __shared__ __align__(16) unsigned Ps[32*132];
  int j0 = blockIdx.x * 128, t0 = blockIdx.y * 128, b = blockIdx.z;
  int tid = threadIdx.x, rg = tid & 15, cg = tid >> 4;
  float acc[8][8];
  #pragma unroll
  for (int i=0;i<8;i++)
    #pragma unroll
    for (int j=0;j<8;j++) acc[i][j]=0.f;
  for (int lc = 0; lc < 8; lc++){
    int l0 = lc*64;
    __syncthreads();
    stage_t128_h (As, S + ((size_t)b*LL + t0)*LL + l0, LL);
    stage_dpack_h(Ps, P + ((size_t)b*LL + l0)*HH + j0, HH);
    __syncthreads();
    rg_inner128_h(As, Ps, acc, rg, cg);
  }
  #pragma unroll
  for (int i=0;i<8;i++){
    int t = t0 + ROW_OF(i,rg);
    #pragma unroll
    for (int j=0;j<8;j++)
      C[((size_t)b*LL + t)*HH + j0 + COL_OF(j,cg)] = acc[i][j];
  }
}

// ---------------- K5: Cg = sigmoid([P|C]@wg^T + bg) * C (fdot2) -----------
__global__ __launch_bounds__(256, 4) void k5_gate(
    const float* __restrict__ P, const float* __restrict__ C,
    const float* __restrict__ wg_w, const float* __restrict__ wg_b,
    float* __restrict__ CG)
{
  __shared__ __align__(16) unsigned Xs[32*132];
  __shared__ __align__(16) unsigned Ws[32*132];
  int r0 = blockIdx.x*128, c0 = blockIdx.y*128;
  int tid = threadIdx.x, rg = tid & 15, cg = tid >> 4;
  float acc[8][8];
  #pragma unroll
  for (int i=0;i<8;i++)
    #pragma unroll
    for (int j=0;j<8;j++) acc[i][j]=0.f;
  for (int kc = 0; kc < 8; kc++){
    const float* Xsrc = (kc < 4) ? (P + (size_t)r0*HH + kc*64)
                                 : (C + (size_t)r0*HH + (kc-4)*64);
    __syncthreads();
    stage_t128_h(Xs, Xsrc, HH);
    stage_t128_h(Ws, wg_w + (size_t)c0*(2*HH) + kc*64, 2*HH);
    __syncthreads();
    rg_inner128_h(Xs, Ws, acc, rg, cg);
  }
  float bj[8];
  #pragma unroll
  for (int j=0;j<8;j++) bj[j] = wg_b[c0 + COL_OF(j,cg)];
  #pragma unroll
  for (int i=0;i<8;i++){
    int r = r0 + ROW_OF(i,rg);
    #pragma unroll
    for (int j=0;j<8;j++){
      int c = c0 + COL_OF(j,cg);
      float g = sigmoid_fast(acc[i][j] + bj[j]);
      CG[(size_t)r*HH + c] = g * C[(size_t)r*HH + c];
    }
  }
}

// ---------------- K6: GI_{l,r} = Cg @ Wih^T + bih (fdot2) -----------------
__global__ __launch_bounds__(256, 4) void k6_gi(
    const float* __restrict__ CG,
    const float* __restrict__ Wih_l, const float* __restrict__ bih_l,
    const float* __restrict__ Wih_r, const float* __restrict__ bih_r,
    float* __restrict__ GIL, float* __restrict__ GIR)
{
  __shared__ __align__(16) unsigned Xs[32*132];
  __shared__ __align__(16) unsigned Ws[32*132];
  int rt = blockIdx.x, ct = blockIdx.y;
  int dir = (ct >= 6);
  const float* Wih = dir ? Wih_r : Wih_l;
  const float* bih = dir ? bih_r : bih_l;
  float* GI = dir ? GIR : GIL;
  int c0 = (ct % 6) * 128, r0 = rt * 128;
  int tid = threadIdx.x, rg = tid & 15, cg = tid >> 4;
  float acc[8][8];
  #pragma unroll
  for (int i=0;i<8;i++)
    #pragma unroll
    for (int j=0;j<8;j++) acc[i][j]=0.f;
  for (int kc = 0; kc < 4; kc++){
    __syncthreads();
    stage_t128_h(Xs, CG + (size_t)r0*HH + kc*64, HH);
    stage_t128_h(Ws, Wih + (size_t)c0*HH + kc*64, HH);
    __syncthreads();
    rg_inner128_h(Xs, Ws, acc, rg, cg);
  }
  float bj[8];
  #pragma unroll
  for (int j=0;j<8;j++) bj[j] = bih[c0 + COL_OF(j,cg)];
  #pragma unroll
  for (int i=0;i<8;i++){
    int r = r0 + ROW_OF(i,rg);
    #pragma unroll
    for (int j=0;j<8;j++)
      GI[(size_t)r*768 + c0 + COL_OF(j,cg)] = acc[i][j] + bj[j];
  }
}

// ---------------- K7: GRU scans (R10, MFMA + 1-barrier schedule) ----------
// 8 blocks = (dir, grp of 8 seqs). Wave w owns cols w*32..w*32+31 of EACH
// gate: nt = g*2+c01 -> B rows g*256 + w*32 + c01*16 + (l&15). A/B share
// the k-rule k = kt*32 + (l>>4)*8 + e (R9-validated). D (m89): col=l&15,
// row=(l>>4)*4+reg = seq -> GRU consumes D regs directly (lanes l<32 =
// seqs 0..7). h fp16 ping-pong in h2T[kt][lq][lr] layout so Af reads are
// lane-consecutive ds_read_b128. gi ring-3 prefetch-2, counted vmcnt
// (19 steady / 16 tail), one raw s_barrier per step.
__global__ __launch_bounds__(512, 2) void k7_scan(
    const float* __restrict__ GIL, const float* __restrict__ GIR,
    const float* __restrict__ Whh_l, const float* __restrict__ bhh_l,
    const float* __restrict__ Whh_r, const float* __restrict__ bhh_r,
    float* __restrict__ out)
{
  int dir = blockIdx.x & 1;
  int grp = blockIdx.x >> 1;          // 0..3
  int t = threadIdx.x;
  int w = t >> 6, l = t & 63;
  int lr = l & 15, lq = l >> 4;
  const float* GI  = dir ? GIR : GIL;
  const float* Whh = dir ? Whh_r : Whh_l;
  const float* bhh = dir ? bhh_r : bhh_l;

  __shared__ __align__(16) float    gi_buf[3][8*768];   // 72 KB
  __shared__ __align__(16) unsigned h2T[2][2048];       // 16 KB: [kt][lq][lr] u32x4
  __shared__ __align__(16) float    bias[768];          // 3 KB

  // B-frags: nt = g*2+c01; Whh row = g*256 + w*32 + c01*16 + lr;
  // k = kt*32 + lq*8 + e (same rule as A -> permutation-safe).
  f16x8 Bf[48];
  #pragma unroll
  for (int g = 0; g < 3; g++)
    #pragma unroll
    for (int c01 = 0; c01 < 2; c01++)
      #pragma unroll
      for (int kt = 0; kt < 8; kt++){
        const float* sp = Whh + (size_t)(g*256 + w*32 + c01*16 + lr)*HH + kt*32 + lq*8;
        float4 a = *(const float4*)sp;
        float4 b = *(const float4*)(sp + 4);
        Bf[(g*2+c01)*8 + kt] = pack8(a, b);
      }
  for (int i = t; i < 2*2048; i += 512) ((unsigned*)h2T)[i] = 0;
  for (int i = t; i < 768;    i += 512) bias[i] = bhh[i];

  // prologue: stage gi for steps 0 and 1
  #pragma unroll
  for (int ps = 0; ps < 2; ps++){
    int tt = dir ? (LL-1-ps) : ps;
    #pragma unroll
    for (int i = 0; i < 3; i++){
      int c = (w*3+i)*64 + l;
      int sq = c/192, q = c - sq*192;
      gload_lds16(GI + ((size_t)(grp*8+sq)*LL + tt)*768 + q*4,
                  &gi_buf[ps][(w*3+i)*256]);
    }
  }
  __syncthreads();   // full drain once (prologue only)

  float hprev[8];
  #pragma unroll
  for (int i=0;i<8;i++) hprev[i]=0.f;
  int cwb = w*32 + lr;

  #pragma unroll 1
  for (int s = 0; s < LL; s++){
    int bi = s - (s/3)*3;
    // [1] issue gi loads for step s+2 (3 x global_load_lds per wave)
    if (s < LL-2){
      int sn = s+2;
      int bn = sn - (sn/3)*3;
      int tt = dir ? (LL-1-sn) : sn;
      #pragma unroll
      for (int i = 0; i < 3; i++){
        int c = (w*3+i)*64 + l;
        int sq = c/192, q = c - sq*192;
        gload_lds16(GI + ((size_t)(grp*8+sq)*LL + tt)*768 + q*4,
                    &gi_buf[bn][(w*3+i)*256]);
      }
    }
    __builtin_amdgcn_sched_barrier(0);   // pin VMEM issue order (loads first)
    // [2] MFMA: kt-outer -> 6 independent chains; Af on the fly
    f32x4 d[6];
    #pragma unroll
    for (int nt=0;nt<6;nt++) d[nt] = (f32x4){0.f,0.f,0.f,0.f};
    {
      const unsigned* hsrc = h2T[s & 1];
      #pragma unroll
      for (int kt = 0; kt < 8; kt++){
        uint4 q = *(const uint4*)&hsrc[kt*256 + l*4];
        f16x8 a = __builtin_bit_cast(f16x8, q);
        #pragma unroll
        for (int nt = 0; nt < 6; nt++)
          d[nt] = __builtin_amdgcn_mfma_f32_16x16x32_f16(a, Bf[nt*8+kt], d[nt], 0, 0, 0);
      }
    }
    // [3] GRU straight from D regs (lanes l<32 = seqs 0..7)
    if (l < 32){
      int tt = dir ? (LL-1-s) : s;
      unsigned short* hdst = (unsigned short*)h2T[(s & 1) ^ 1];
      const float* gb = gi_buf[bi];
      #pragma unroll
      for (int c01 = 0; c01 < 2; c01++){
        int cw = cwb + c01*16;
        float bR = bias[      cw];
        float bZ = bias[256 + cw];
        float bN = bias[512 + cw];
        int kt2 = cw >> 5, lq2 = (cw >> 3) & 3, e2 = cw & 7;
        #pragma unroll
        for (int r = 0; r < 4; r++){
          int sr = lq*4 + r;           // 0..7
          float gr = gb[sr*768 +       cw];
          float gz = gb[sr*768 + 256 + cw];
          float gn = gb[sr*768 + 512 + cw];
          float rv = sigmoid_fast(gr + d[c01  ][r] + bR);
          float zv = sigmoid_fast(gz + d[2+c01][r] + bZ);
          float nv = tanh_fast  (gn + rv*(d[4+c01][r] + bN));
          float hp = hprev[c01*4 + r];
          float hn = zv*(hp - nv) + nv;
          hprev[c01*4 + r] = hn;
          out[((size_t)(grp*8+sr)*LL + tt)*(2*HH) + dir*HH + cw] = hn;
          hdst[((kt2*4 + lq2)*16 + sr)*8 + e2] =
              __builtin_bit_cast(unsigned short, (_Float16)hn);
        }
      }
    }
    __builtin_amdgcn_sched_barrier(0);
    // [4] counted waits + single raw barrier. Per wave per step VMEM =
    // 3 loads + 8 stores (order pinned). Target: ld3(s+1) [issued step
    // s-1] done -> insts after = st8(s-1)+ld3(s+2)+st8(s) = 19.
    // Tail (s=LL-2): no ld3(s+2) -> 16. Last step: nothing to wait.
    if (s < LL-2)      asm volatile("s_waitcnt vmcnt(19)" ::: "memory");
    else if (s==LL-2)  asm volatile("s_waitcnt vmcnt(16)" ::: "memory");
    asm volatile("s_waitcnt lgkmcnt(0)" ::: "memory");
    __builtin_amdgcn_s_barrier();
    __builtin_amdgcn_sched_barrier(0);
  }
}

extern "C" void kernel_launch(void* const* d_in, const int* in_sizes, int n_in,
                              void* d_out, int out_size, void* d_ws, size_t ws_size,
                              hipStream_t stream)
{
  const float* P    = (const float*)d_in[0];
  const float* wq_w = (const float*)d_in[1];
  const float* wq_b = (const float*)d_in[2];
  const float* wp_w = (const float*)d_in[3];
  const float* wp_b = (const float*)d_in[4];
  const float* ws_w = (const float*)d_in[5];
  // d_in[6] = ws_b: softmax-invariant, unused
  const float* wg_w = (const float*)d_in[7];
  const float* wg_b = (const float*)d_in[8];
  const float* Wih_l= (const float*)d_in[9];
  const float* Whh_l= (const float*)d_in[10];
  const float* bih_l= (const float*)d_in[11];
  const float* bhh_l= (const float*)d_in[12];
  const float* Wih_r= (const float*)d_in[13];
  const float* Whh_r= (const float*)d_in[14];
  const float* bih_r= (const float*)d_in[15];
  const float* bhh_r= (const float*)d_in[16];

  float* ws  = (float*)d_ws;
  float* HQ  = ws;                    //  4,194,304
  float* PP  = ws + 4194304;          //  4,194,304
  float* S   = ws + 8388608;          //  8,388,608
  float* C   = ws + 16777216;         //  4,194,304
  float* CG  = ws + 20971520;         //  4,194,304
  float* GIR = ws + 25165824;         // 12,582,912
  float* GIL = ws;                    // 12,582,912 (aliases HQ/PP/S-front; dead by k6)
  float* out = (float*)d_out;

  k1_hq_pp  <<<dim3(128, 4),    256, 0, stream>>>(P, wq_w, wq_b, wp_w, wp_b, HQ, PP);
  k2_scores <<<dim3(16, 32),    256, 0, stream>>>(HQ, PP, ws_w, S);
  k3_softmax<<<4096,            256, 0, stream>>>(S);
  k4_context<<<dim3(2, 4, 32),  256, 0, stream>>>(S, P, C);
  k5_gate   <<<dim3(128, 2),    256, 0, stream>>>(P, C, wg_w, wg_b, CG);
  k6_gi     <<<dim3(128, 12),   256, 0, stream>>>(CG, Wih_l, bih_l, Wih_r, bih_r, GIL, GIR);
  k7_scan   <<<8,               512, 0, stream>>>(GIL, GIR, Whh_l, bhh_l, Whh_r, bhh_r, out);
}

// Round 13
// 1488.442 us; speedup vs baseline: 1.9499x; 1.9499x over previous
//
#include <hip/hip_runtime.h>
#include <cstdint>

// SelfMatchingLayer: B=32, L=512, H=256, fp32.
// R11 = REVERT to R8 (measured best: total 1485.9us, k7 645us, round 7).
//   k7 history: 762 (R3 butterfly) -> 645 (R8: 512thr fdot2, 192-u32
//   weights, paced staging) -> 1008 (R9 MFMA, 2 full-drain barriers) ->
//   1982 (R10 MFMA + hand-sched: GRU parallelism halved to 256 thr x 8
//   outputs, 24 scalar ds_reads/thread latency-exposed, 8-block lockstep
//   = zero latency hiding). Both MFMA structures lost to fdot2+spill;
//   allocator never grants >128 arch VGPRs (R5-R8), LDS-resident weights
//   cost 147KB/step LDS BW (analytically worse). Banking the best.

#define LL 512
#define HH 256

typedef _Float16 half2_t __attribute__((ext_vector_type(2)));

__device__ __forceinline__ float exp2f_fast(float x){
#if defined(__HIP_DEVICE_COMPILE__)
  return __builtin_amdgcn_exp2f(x);
#else
  return exp2f(x);
#endif
}
__device__ __forceinline__ float rcpf_fast(float x){
#if defined(__HIP_DEVICE_COMPILE__)
  return __builtin_amdgcn_rcpf(x);
#else
  return 1.0f/x;
#endif
}
__device__ __forceinline__ float tanh_fast(float x){
  float e = exp2f_fast(x * 2.885390081777927f);   // 2*log2(e)
  return 1.0f - 2.0f * rcpf_fast(1.0f + e);
}
__device__ __forceinline__ float sigmoid_fast(float x){
  return rcpf_fast(1.0f + exp2f_fast(x * -1.4426950408889634f));
}

#define SCALE_K2 2.885390081777927f   // 2*log2(e)

#if defined(__HIP_DEVICE_COMPILE__) && __has_builtin(__builtin_amdgcn_fdot2)
#define USE_FDOT2 1
#endif

__device__ __forceinline__ float dot2_acc(unsigned wb, unsigned hb, float a){
  half2_t wv = __builtin_bit_cast(half2_t, wb);
  half2_t hv = __builtin_bit_cast(half2_t, hb);
#ifdef USE_FDOT2
  return __builtin_amdgcn_fdot2(wv, hv, a, false);
#else
  return a + (float)wv.x*(float)hv.x + (float)wv.y*(float)hv.y;
#endif
}

__device__ __forceinline__ unsigned pack2h(float a, float b){
  half2_t h = { (_Float16)a, (_Float16)b };
  return __builtin_bit_cast(unsigned, h);
}

// ==== fp32 128x128-tile GEMM helpers (k1 only) ===========================
__device__ __forceinline__ void stage_t128(float* Ls, const float* g, int ldg){
  int tid = threadIdx.x;
  int r = tid >> 4, kq = (tid & 15) * 4;
  #pragma unroll
  for (int it = 0; it < 8; it++){
    int rr = r + 16*it;
    float4 v = *(const float4*)(g + (size_t)rr*ldg + kq);
    Ls[(kq+0)*132 + rr] = v.x;
    Ls[(kq+1)*132 + rr] = v.y;
    Ls[(kq+2)*132 + rr] = v.z;
    Ls[(kq+3)*132 + rr] = v.w;
  }
}
__device__ __forceinline__ void rg_inner128(const float* Xs, const float* Ws,
                                            float (&acc)[8][8], int rg, int cg){
  #pragma unroll 2
  for (int k = 0; k < 64; k++){
    const float* xr = Xs + k*132;
    const float* wr = Ws + k*132;
    float4 x0 = *(const float4*)(xr + rg*4);
    float4 x1 = *(const float4*)(xr + 64 + rg*4);
    float4 w0 = *(const float4*)(wr + cg*4);
    float4 w1 = *(const float4*)(wr + 64 + cg*4);
    float xv[8] = {x0.x,x0.y,x0.z,x0.w, x1.x,x1.y,x1.z,x1.w};
    float wv[8] = {w0.x,w0.y,w0.z,w0.w, w1.x,w1.y,w1.z,w1.w};
    #pragma unroll
    for (int i=0;i<8;i++)
      #pragma unroll
      for (int j=0;j<8;j++)
        acc[i][j] = fmaf(xv[i], wv[j], acc[i][j]);
  }
}
#define ROW_OF(i, rg) ((rg)*4 + ((i)&3) + ((i)>>2)*64)
#define COL_OF(j, cg) ((cg)*4 + ((j)&3) + ((j)>>2)*64)

// ==== packed-fp16 128x128-tile GEMM helpers (k4/k5/k6) ===================
__device__ __forceinline__ void stage_t128_h(unsigned* Ls, const float* g, int ldg){
  int tid = threadIdx.x;
  int r = tid >> 4, kq = (tid & 15) * 4;
  #pragma unroll
  for (int it = 0; it < 8; it++){
    int rr = r + 16*it;
    float4 v = *(const float4*)(g + (size_t)rr*ldg + kq);
    Ls[((kq>>1)+0)*132 + rr] = pack2h(v.x, v.y);
    Ls[((kq>>1)+1)*132 + rr] = pack2h(v.z, v.w);
  }
}
__device__ __forceinline__ void stage_dpack_h(unsigned* Ls, const float* g, int ldg){
  int tid = threadIdx.x;
  int kr = tid >> 5, eq = (tid & 31) * 4;
  #pragma unroll
  for (int it = 0; it < 4; it++){
    int lp = kr + 8*it;
    float4 a = *(const float4*)(g + (size_t)(2*lp  )*ldg + eq);
    float4 b = *(const float4*)(g + (size_t)(2*lp+1)*ldg + eq);
    uint4 o;
    o.x = pack2h(a.x, b.x);
    o.y = pack2h(a.y, b.y);
    o.z = pack2h(a.z, b.z);
    o.w = pack2h(a.w, b.w);
    *(uint4*)(Ls + lp*132 + eq) = o;
  }
}
__device__ __forceinline__ void rg_inner128_h(const unsigned* Xs, const unsigned* Ws,
                                              float (&acc)[8][8], int rg, int cg){
  #pragma unroll 2
  for (int kp = 0; kp < 32; kp++){
    const unsigned* xr = Xs + kp*132;
    const unsigned* wr = Ws + kp*132;
    uint4 x0 = *(const uint4*)(xr + rg*4);
    uint4 x1 = *(const uint4*)(xr + 64 + rg*4);
    uint4 w0 = *(const uint4*)(wr + cg*4);
    uint4 w1 = *(const uint4*)(wr + 64 + cg*4);
    unsigned xv[8] = {x0.x,x0.y,x0.z,x0.w, x1.x,x1.y,x1.z,x1.w};
    unsigned wv[8] = {w0.x,w0.y,w0.z,w0.w, w1.x,w1.y,w1.z,w1.w};
    #pragma unroll
    for (int i=0;i<8;i++)
      #pragma unroll
      for (int j=0;j<8;j++)
        acc[i][j] = dot2_acc(xv[i], wv[j], acc[i][j]);
  }
}

// ---------------- K1: HQ' = SC*(P@wq^T+bq) ; PP' = SC*(P@wp^T+bp) --------
__global__ __launch_bounds__(256) void k1_hq_pp(
    const float* __restrict__ P,
    const float* __restrict__ wq_w, const float* __restrict__ wq_b,
    const float* __restrict__ wp_w, const float* __restrict__ wp_b,
    float* __restrict__ HQ, float* __restrict__ PP)
{
  __shared__ __align__(16) float Xs[64*132];
  __shared__ __align__(16) float Ws[64*132];
  int rt = blockIdx.x, ct = blockIdx.y;
  const float* W  = (ct < 2) ? wq_w : wp_w;
  const float* Bv = (ct < 2) ? wq_b : wp_b;
  float* O = (ct < 2) ? HQ : PP;
  int c0 = (ct & 1) * 128, r0 = rt * 128;
  int tid = threadIdx.x, rg = tid & 15, cg = tid >> 4;
  float acc[8][8];
  #pragma unroll
  for (int i=0;i<8;i++)
    #pragma unroll
    for (int j=0;j<8;j++) acc[i][j]=0.f;
  for (int kc = 0; kc < 4; kc++){
    __syncthreads();
    stage_t128(Xs, P + (size_t)r0*HH + kc*64, HH);
    stage_t128(Ws, W + (size_t)c0*HH + kc*64, HH);
    __syncthreads();
    rg_inner128(Xs, Ws, acc, rg, cg);
  }
  float bj[8];
  #pragma unroll
  for (int j=0;j<8;j++) bj[j] = Bv[c0 + COL_OF(j,cg)];
  #pragma unroll
  for (int i=0;i<8;i++){
    int r = r0 + ROW_OF(i,rg);
    #pragma unroll
    for (int j=0;j<8;j++)
      O[(size_t)r*HH + c0 + COL_OF(j,cg)] = SCALE_K2 * (acc[i][j] + bj[j]);
  }
}

// ---------------- K2: S_eff[b,t,l] = -2 * sum_h w_h / (1 + exp2(HQ'+PP')) -
__global__ __launch_bounds__(256) void k2_scores(
    const float* __restrict__ HQ, const float* __restrict__ PP,
    const float* __restrict__ ws_w, float* __restrict__ S)
{
  __shared__ float Hq_c[128*65];
  __shared__ float Pp_c[32*65];
  __shared__ float wsl[256];
  int tid = threadIdx.x;
  int b = blockIdx.y, t0 = blockIdx.x * 32;
  wsl[tid] = ws_w[tid];
  int tg = tid >> 6;
  int lg = tid & 63;
  for (int lc = 0; lc < 4; lc++){
    float acc[8][2];
    #pragma unroll
    for (int i=0;i<8;i++){ acc[i][0]=0.f; acc[i][1]=0.f; }
    for (int hc = 0; hc < 4; hc++){
      __syncthreads();
      {
        int r = tid >> 4, kq = (tid & 15) * 4;
        #pragma unroll
        for (int it=0; it<2; it++){
          int t = r + 16*it;
          float4 v = *(const float4*)(PP + ((size_t)b*LL + t0 + t)*HH + hc*64 + kq);
          float* d = Pp_c + t*65 + kq;
          d[0]=v.x; d[1]=v.y; d[2]=v.z; d[3]=v.w;
        }
      }
      {
        int r = tid >> 4, kq = (tid & 15) * 4;
        #pragma unroll
        for (int it=0; it<8; it++){
          int l = r + 16*it;
          float4 v = *(const float4*)(HQ + ((size_t)b*LL + lc*128 + l)*HH + hc*64 + kq);
          float* d = Hq_c + l*65 + kq;
          d[0]=v.x; d[1]=v.y; d[2]=v.z; d[3]=v.w;
        }
      }
      __syncthreads();
      #pragma unroll 2
      for (int h = 0; h < 64; h++){
        float w = wsl[hc*64 + h];
        float pp[8], hq[2];
        #pragma unroll
        for (int i=0;i<8;i++) pp[i] = Pp_c[(tg + 4*i)*65 + h];
        #pragma unroll
        for (int j=0;j<2;j++) hq[j] = Hq_c[(2*lg + j)*65 + h];
        #pragma unroll
        for (int i=0;i<8;i++)
          #pragma unroll
          for (int j=0;j<2;j++){
            float e = exp2f_fast(pp[i] + hq[j]);
            acc[i][j] = fmaf(w, rcpf_fast(1.0f + e), acc[i][j]);
          }
      }
    }
    #pragma unroll
    for (int i=0;i<8;i++)
      #pragma unroll
      for (int j=0;j<2;j++)
        S[((size_t)b*LL + t0 + tg + 4*i)*LL + lc*128 + 2*lg + j] = -2.0f*acc[i][j];
    __syncthreads();
  }
}

// ---------------- K3: softmax over l, in place; one wave per row ----------
__global__ __launch_bounds__(256) void k3_softmax(float* __restrict__ S)
{
  int wave = threadIdx.x >> 6, lane = threadIdx.x & 63;
  size_t row = (size_t)blockIdx.x*4 + wave;
  float* p = S + row*LL;
  float v[8];
  #pragma unroll
  for (int i=0;i<8;i++) v[i] = p[lane + 64*i];
  float m = v[0];
  #pragma unroll
  for (int i=1;i<8;i++) m = fmaxf(m, v[i]);
  #pragma unroll
  for (int off=32; off>=1; off>>=1) m = fmaxf(m, __shfl_xor(m, off, 64));
  float s = 0.f;
  #pragma unroll
  for (int i=0;i<8;i++){ v[i] = exp2f_fast((v[i]-m)*1.4426950408889634f); s += v[i]; }
  #pragma unroll
  for (int off=32; off>=1; off>>=1) s += __shfl_xor(s, off, 64);
  float inv = 1.0f / s;
  #pragma unroll
  for (int i=0;i<8;i++) p[lane + 64*i] = v[i]*inv;
}

// ---------------- K4: C[b,t,:] = attn[b,t,:] @ P[b,:,:] (fdot2) -----------
__global__ __launch_bounds__(256, 4) void k4_context(
    const float* __restrict__ S, const float* __restrict__ P, float* __restrict__ C)
{
  __shared__ __align__(16) unsigned As[32*132];
  __shared__ __align__(16) unsigned Ps[32*132];
  int j0 = blockIdx.x * 128, t0 = blockIdx.y * 128, b = blockIdx.z;
  int tid = threadIdx.x, rg = tid & 15, cg = tid >> 4;
  float acc[8][8];
  #pragma unroll
  for (int i=0;i<8;i++)
    #pragma unroll
    for (int j=0;j<8;j++) acc[i][j]=0.f;
  for (int lc = 0; lc < 8; lc++){
    int l0 = lc*64;
    __syncthreads();
    stage_t128_h (As, S + ((size_t)b*LL + t0)*LL + l0, LL);
    stage_dpack_h(Ps, P + ((size_t)b*LL + l0)*HH + j0, HH);
    __syncthreads();
    rg_inner128_h(As, Ps, acc, rg, cg);
  }
  #pragma unroll
  for (int i=0;i<8;i++){
    int t = t0 + ROW_OF(i,rg);
    #pragma unroll
    for (int j=0;j<8;j++)
      C[((size_t)b*LL + t)*HH + j0 + COL_OF(j,cg)] = acc[i][j];
  }
}

// ---------------- K5: Cg = sigmoid([P|C]@wg^T + bg) * C (fdot2) -----------
__global__ __launch_bounds__(256, 4) void k5_gate(
    const float* __restrict__ P, const float* __restrict__ C,
    const float* __restrict__ wg_w, const float* __restrict__ wg_b,
    float* __restrict__ CG)
{
  __shared__ __align__(16) unsigned Xs[32*132];
  __shared__ __align__(16) unsigned Ws[32*132];
  int r0 = blockIdx.x*128, c0 = blockIdx.y*128;
  int tid = threadIdx.x, rg = tid & 15, cg = tid >> 4;
  float acc[8][8];
  #pragma unroll
  for (int i=0;i<8;i++)
    #pragma unroll
    for (int j=0;j<8;j++) acc[i][j]=0.f;
  for (int kc = 0; kc < 8; kc++){
    const float* Xsrc = (kc < 4) ? (P + (size_t)r0*HH + kc*64)
                                 : (C + (size_t)r0*HH + (kc-4)*64);
    __syncthreads();
    stage_t128_h(Xs, Xsrc, HH);
    stage_t128_h(Ws, wg_w + (size_t)c0*(2*HH) + kc*64, 2*HH);
    __syncthreads();
    rg_inner128_h(Xs, Ws, acc, rg, cg);
  }
  float bj[8];
  #pragma unroll
  for (int j=0;j<8;j++) bj[j] = wg_b[c0 + COL_OF(j,cg)];
  #pragma unroll
  for (int i=0;i<8;i++){
    int r = r0 + ROW_OF(i,rg);
    #pragma unroll
    for (int j=0;j<8;j++){
      int c = c0 + COL_OF(j,cg);
      float g = sigmoid_fast(acc[i][j] + bj[j]);
      CG[(size_t)r*HH + c] = g * C[(size_t)r*HH + c];
    }
  }
}

// ---------------- K6: GI_{l,r} = Cg @ Wih^T + bih (fdot2) -----------------
__global__ __launch_bounds__(256, 4) void k6_gi(
    const float* __restrict__ CG,
    const float* __restrict__ Wih_l, const float* __restrict__ bih_l,
    const float* __restrict__ Wih_r, const float* __restrict__ bih_r,
    float* __restrict__ GIL, float* __restrict__ GIR)
{
  __shared__ __align__(16) unsigned Xs[32*132];
  __shared__ __align__(16) unsigned Ws[32*132];
  int rt = blockIdx.x, ct = blockIdx.y;
  int dir = (ct >= 6);
  const float* Wih = dir ? Wih_r : Wih_l;
  const float* bih = dir ? bih_r : bih_l;
  float* GI = dir ? GIR : GIL;
  int c0 = (ct % 6) * 128, r0 = rt * 128;
  int tid = threadIdx.x, rg = tid & 15, cg = tid >> 4;
  float acc[8][8];
  #pragma unroll
  for (int i=0;i<8;i++)
    #pragma unroll
    for (int j=0;j<8;j++) acc[i][j]=0.f;
  for (int kc = 0; kc < 4; kc++){
    __syncthreads();
    stage_t128_h(Xs, CG + (size_t)r0*HH + kc*64, HH);
    stage_t128_h(Ws, Wih + (size_t)c0*HH + kc*64, HH);
    __syncthreads();
    rg_inner128_h(Xs, Ws, acc, rg, cg);
  }
  float bj[8];
  #pragma unroll
  for (int j=0;j<8;j++) bj[j] = bih[c0 + COL_OF(j,cg)];
  #pragma unroll
  for (int i=0;i<8;i++){
    int r = r0 + ROW_OF(i,rg);
    #pragma unroll
    for (int j=0;j<8;j++)
      GI[(size_t)r*768 + c0 + COL_OF(j,cg)] = acc[i][j] + bj[j];
  }
}

// ---------------- K7: GRU scans (R8 = R6 + pacing; measured 645us) --------
// 64 blocks (b,dir) x 512 threads. Thread t: u = t>>1, ks = t&1 (k half).
// Gate rows {u,u+256,u+512} over k in [ks*128, +128): 64 u32 weights/gate,
// 192 total. Pacing: staging 3 rounds x 4 float4; h-reads 4 sub-chunks x
// 4 uint4; weight preload 8 rounds x (3x8 float2). One barrier per step.
__global__ __launch_bounds__(512, 2) void k7_scan(
    const float* __restrict__ GIL, const float* __restrict__ GIR,
    const float* __restrict__ Whh_l, const float* __restrict__ bhh_l,
    const float* __restrict__ Whh_r, const float* __restrict__ bhh_r,
    float* __restrict__ out)
{
  int b   = blockIdx.x >> 1;
  int dir = blockIdx.x & 1;
  int t   = threadIdx.x;
  int u   = t >> 1;          // output dim 0..255
  int ks  = t & 1;           // k half
  int k0  = ks * 128;
  const float* GI  = dir ? GIR : GIL;
  const float* Whh = dir ? Whh_r : Whh_l;
  const float* bhh = dir ? bhh_r : bhh_l;

  unsigned w_r[64], w_z[64], w_n[64];
  {
    const float2* wr = (const float2*)(Whh + (size_t)(u      )*HH + k0);
    const float2* wz = (const float2*)(Whh + (size_t)(u + 256)*HH + k0);
    const float2* wn = (const float2*)(Whh + (size_t)(u + 512)*HH + k0);
    #pragma unroll
    for (int pc = 0; pc < 8; pc++){
      #pragma unroll
      for (int p = pc*8; p < pc*8+8; p++){ float2 a = wr[p]; w_r[p] = pack2h(a.x, a.y); }
      __builtin_amdgcn_sched_barrier(0);
      #pragma unroll
      for (int p = pc*8; p < pc*8+8; p++){ float2 a = wz[p]; w_z[p] = pack2h(a.x, a.y); }
      __builtin_amdgcn_sched_barrier(0);
      #pragma unroll
      for (int p = pc*8; p < pc*8+8; p++){ float2 a = wn[p]; w_n[p] = pack2h(a.x, a.y); }
      __builtin_amdgcn_sched_barrier(0);
    }
  }
  float b_r = bhh[u], b_z = bhh[u + 256], b_n = bhh[u + 512];

  __shared__ __align__(16) unsigned hsbuf[2][128];   // fp16 h, ping-pong
  __shared__ __align__(16) float gi_buf[32*768];     // 96 KB
  __shared__ __align__(16) float out_buf[32*256];    // 32 KB
  if (t < 128){ hsbuf[0][t] = 0; }

  float hprev = 0.f;

  #pragma unroll 1
  for (int chunk = 0; chunk < 16; chunk++){
    int s0 = chunk * 32;
    int tlo = dir ? (LL - s0 - 32) : s0;    // staged t range [tlo, tlo+31]
    {
      const float4* src = (const float4*)(GI + ((size_t)b*LL + tlo)*768);
      float4* dst = (float4*)gi_buf;
      #pragma unroll
      for (int rd = 0; rd < 3; rd++){
        float4 v0 = src[t + 512*(4*rd+0)];
        float4 v1 = src[t + 512*(4*rd+1)];
        float4 v2 = src[t + 512*(4*rd+2)];
        float4 v3 = src[t + 512*(4*rd+3)];
        dst[t + 512*(4*rd+0)] = v0;
        dst[t + 512*(4*rd+1)] = v1;
        dst[t + 512*(4*rd+2)] = v2;
        dst[t + 512*(4*rd+3)] = v3;
        __builtin_amdgcn_sched_barrier(0);
      }
    }
    __syncthreads();   // gi_buf ready; hs writes from prev step visible

    #pragma unroll 1
    for (int p = 0; p < 32; p++){
      int s = s0 + p;
      int tt = dir ? (LL-1-s) : s;
      int gidx = tt - tlo;                  // 0..31
      float ar0=0.f, ar1=0.f, az0=0.f, az1=0.f, an0=0.f, an1=0.f;
      #pragma unroll
      for (int sc = 0; sc < 4; sc++){
        const uint4* hp = (const uint4*)(hsbuf[s & 1]) + ks*16 + sc*4;
        uint4 q0 = hp[0], q1 = hp[1], q2 = hp[2], q3 = hp[3];
        unsigned hv[16] = {q0.x,q0.y,q0.z,q0.w, q1.x,q1.y,q1.z,q1.w,
                           q2.x,q2.y,q2.z,q2.w, q3.x,q3.y,q3.z,q3.w};
        #pragma unroll
        for (int j = 0; j < 16; j += 2){
          int pp = sc*16 + j;
          ar0 = dot2_acc(w_r[pp  ], hv[j  ], ar0);
          az0 = dot2_acc(w_z[pp  ], hv[j  ], az0);
          an0 = dot2_acc(w_n[pp  ], hv[j  ], an0);
          ar1 = dot2_acc(w_r[pp+1], hv[j+1], ar1);
          az1 = dot2_acc(w_z[pp+1], hv[j+1], az1);
          an1 = dot2_acc(w_n[pp+1], hv[j+1], an1);
        }
        __builtin_amdgcn_sched_barrier(0);
      }
      float ar = ar0 + ar1, az = az0 + az1, an = an0 + an1;
      ar += __shfl_xor(ar, 1, 64);
      az += __shfl_xor(az, 1, 64);
      an += __shfl_xor(an, 1, 64);
      const float* g = gi_buf + (size_t)gidx*768;
      float r  = sigmoid_fast(g[u      ] + ar + b_r);
      float z  = sigmoid_fast(g[u + 256] + az + b_z);
      float n  = tanh_fast  (g[u + 512] + r*(an + b_n));
      float hn = z*(hprev - n) + n;
      hprev = hn;
      if (ks == 0){
        out_buf[p*256 + u] = hn;
        ((unsigned short*)hsbuf[(s & 1) ^ 1])[u] =
            __builtin_bit_cast(unsigned short, (_Float16)hn);
      }
      __syncthreads();   // hs(write-buf) ready; separates reads from next writes
    }
    #pragma unroll
    for (int fr = 0; fr < 4; fr++){
      #pragma unroll
      for (int q = 0; q < 4; q++){
        int i = t + 512*(fr*4 + q);
        int p = i >> 8, uu = i & 255;
        int s = s0 + p;
        int tt = dir ? (LL-1-s) : s;
        out[((size_t)b*LL + tt)*(2*HH) + dir*HH + uu] = out_buf[i];
      }
      __builtin_amdgcn_sched_barrier(0);
    }
    __syncthreads();   // out_buf/gi_buf safe to reuse
  }
}

extern "C" void kernel_launch(void* const* d_in, const int* in_sizes, int n_in,
                              void* d_out, int out_size, void* d_ws, size_t ws_size,
                              hipStream_t stream)
{
  const float* P    = (const float*)d_in[0];
  const float* wq_w = (const float*)d_in[1];
  const float* wq_b = (const float*)d_in[2];
  const float* wp_w = (const float*)d_in[3];
  const float* wp_b = (const float*)d_in[4];
  const float* ws_w = (const float*)d_in[5];
  // d_in[6] = ws_b: softmax-invariant, unused
  const float* wg_w = (const float*)d_in[7];
  const float* wg_b = (const float*)d_in[8];
  const float* Wih_l= (const float*)d_in[9];
  const float* Whh_l= (const float*)d_in[10];
  const float* bih_l= (const float*)d_in[11];
  const float* bhh_l= (const float*)d_in[12];
  const float* Wih_r= (const float*)d_in[13];
  const float* Whh_r= (const float*)d_in[14];
  const float* bih_r= (const float*)d_in[15];
  const float* bhh_r= (const float*)d_in[16];

  float* ws  = (float*)d_ws;
  float* HQ  = ws;                    //  4,194,304
  float* PP  = ws + 4194304;          //  4,194,304
  float* S   = ws + 8388608;          //  8,388,608
  float* C   = ws + 16777216;         //  4,194,304
  float* CG  = ws + 20971520;         //  4,194,304
  float* GIR = ws + 25165824;         // 12,582,912
  float* GIL = ws;                    // 12,582,912 (aliases HQ/PP/S-front; dead by k6)
  float* out = (float*)d_out;

  k1_hq_pp  <<<dim3(128, 4),    256, 0, stream>>>(P, wq_w, wq_b, wp_w, wp_b, HQ, PP);
  k2_scores <<<dim3(16, 32),    256, 0, stream>>>(HQ, PP, ws_w, S);
  k3_softmax<<<4096,            256, 0, stream>>>(S);
  k4_context<<<dim3(2, 4, 32),  256, 0, stream>>>(S, P, C);
  k5_gate   <<<dim3(128, 2),    256, 0, stream>>>(P, C, wg_w, wg_b, CG);
  k6_gi     <<<dim3(128, 12),   256, 0, stream>>>(CG, Wih_l, bih_l, Wih_r, bih_r, GIL, GIR);
  k7_scan   <<<64,              512, 0, stream>>>(GIL, GIR, Whh_l, bhh_l, Whh_r, bhh_r, out);
}

// Round 17
// 1333.660 us; speedup vs baseline: 2.1762x; 1.1161x over previous
//
#include <hip/hip_runtime.h>
#include <cstdint>

// SelfMatchingLayer: B=32, L=512, H=256, fp32.
// R12 (4th submit; broker timeouts r14/r15, container failure r16 -- never
//      ran): k4/k5/k6 converted from fdot2 (4 FLOP/instr) to MFMA 16x16x32
//      f16 (16384 FLOP/instr), using the fragment conventions END-TO-END
//      VALIDATED by R9 on this problem: A row=l&15 k=kt*32+(l>>4)*8+e;
//      B col=l&15 same k-rule (shared bijection cancels); D col=l&15
//      row=(l>>4)*4+reg. 128x128 tiles, BK=64, 4 waves x 32 cols, LDS
//      [row][36] u32 k-pair layout (144B stride: 16B-aligned b128, 2-way
//      banks). k4 B=P[l][j] transpose-packed; k5/k6 B=W[c][k] direct-
//      packed. k1 (feeds exp2) fp32; k2/k3/k7 unchanged (k7 = measured-
//      best R8 fdot2 645us).

#define LL 512
#define HH 256

typedef _Float16 half2_t __attribute__((ext_vector_type(2)));
typedef _Float16 f16x8   __attribute__((ext_vector_type(8)));
typedef float    f32x4   __attribute__((ext_vector_type(4)));

__device__ __forceinline__ float exp2f_fast(float x){
#if defined(__HIP_DEVICE_COMPILE__)
  return __builtin_amdgcn_exp2f(x);
#else
  return exp2f(x);
#endif
}
__device__ __forceinline__ float rcpf_fast(float x){
#if defined(__HIP_DEVICE_COMPILE__)
  return __builtin_amdgcn_rcpf(x);
#else
  return 1.0f/x;
#endif
}
__device__ __forceinline__ float tanh_fast(float x){
  float e = exp2f_fast(x * 2.885390081777927f);   // 2*log2(e)
  return 1.0f - 2.0f * rcpf_fast(1.0f + e);
}
__device__ __forceinline__ float sigmoid_fast(float x){
  return rcpf_fast(1.0f + exp2f_fast(x * -1.4426950408889634f));
}

#define SCALE_K2 2.885390081777927f   // 2*log2(e)

#if defined(__HIP_DEVICE_COMPILE__) && __has_builtin(__builtin_amdgcn_fdot2)
#define USE_FDOT2 1
#endif

__device__ __forceinline__ float dot2_acc(unsigned wb, unsigned hb, float a){
  half2_t wv = __builtin_bit_cast(half2_t, wb);
  half2_t hv = __builtin_bit_cast(half2_t, hb);
#ifdef USE_FDOT2
  return __builtin_amdgcn_fdot2(wv, hv, a, false);
#else
  return a + (float)wv.x*(float)hv.x + (float)wv.y*(float)hv.y;
#endif
}

__device__ __forceinline__ unsigned pack2h(float a, float b){
  half2_t h = { (_Float16)a, (_Float16)b };
  return __builtin_bit_cast(unsigned, h);
}

// ==== fp32 128x128-tile GEMM helpers (k1 only) ===========================
__device__ __forceinline__ void stage_t128(float* Ls, const float* g, int ldg){
  int tid = threadIdx.x;
  int r = tid >> 4, kq = (tid & 15) * 4;
  #pragma unroll
  for (int it = 0; it < 8; it++){
    int rr = r + 16*it;
    float4 v = *(const float4*)(g + (size_t)rr*ldg + kq);
    Ls[(kq+0)*132 + rr] = v.x;
    Ls[(kq+1)*132 + rr] = v.y;
    Ls[(kq+2)*132 + rr] = v.z;
    Ls[(kq+3)*132 + rr] = v.w;
  }
}
__device__ __forceinline__ void rg_inner128(const float* Xs, const float* Ws,
                                            float (&acc)[8][8], int rg, int cg){
  #pragma unroll 2
  for (int k = 0; k < 64; k++){
    const float* xr = Xs + k*132;
    const float* wr = Ws + k*132;
    float4 x0 = *(const float4*)(xr + rg*4);
    float4 x1 = *(const float4*)(xr + 64 + rg*4);
    float4 w0 = *(const float4*)(wr + cg*4);
    float4 w1 = *(const float4*)(wr + 64 + cg*4);
    float xv[8] = {x0.x,x0.y,x0.z,x0.w, x1.x,x1.y,x1.z,x1.w};
    float wv[8] = {w0.x,w0.y,w0.z,w0.w, w1.x,w1.y,w1.z,w1.w};
    #pragma unroll
    for (int i=0;i<8;i++)
      #pragma unroll
      for (int j=0;j<8;j++)
        acc[i][j] = fmaf(xv[i], wv[j], acc[i][j]);
  }
}
#define ROW_OF(i, rg) ((rg)*4 + ((i)&3) + ((i)>>2)*64)
#define COL_OF(j, cg) ((cg)*4 + ((j)&3) + ((j)>>2)*64)

// ==== MFMA 128x128-tile GEMM helpers (k4/k5/k6) ==========================
// LDS: [128 rows][LDK u32] k-pair layout; row stride 36 u32 = 144 B
// (multiple of 16 -> b128-aligned; 36 mod 32 = 4 -> 2-way banks, free).
#define LDK 36

// direct pack: src [row][k] fp32 (128 rows x 64 k) -> Ls[row][kp]
__device__ __forceinline__ void mstage_direct(unsigned* Ls, const float* g, int ldg){
  int tid = threadIdx.x;
  int row = tid >> 1, half = tid & 1;
  const float4* s = (const float4*)(g + (size_t)row*ldg + half*32);
  unsigned* d = Ls + row*LDK + half*16;
  #pragma unroll
  for (int i = 0; i < 8; i += 2){
    float4 a = s[i], b = s[i+1];
    uint4 o;
    o.x = pack2h(a.x,a.y); o.y = pack2h(a.z,a.w);
    o.z = pack2h(b.x,b.y); o.w = pack2h(b.z,b.w);
    *(uint4*)(d + i*2) = o;
  }
}
// transpose pack (k4 B): src [k 64][c 128] fp32 -> Ls[c][kp]
__device__ __forceinline__ void mstage_trans(unsigned* Ls, const float* g, int ldg){
  int tid = threadIdx.x;
  int j = (tid & 31) * 4, kq = tid >> 5;
  #pragma unroll
  for (int it = 0; it < 4; it++){
    int kp = kq*4 + it;
    float4 a = *(const float4*)(g + (size_t)(2*kp  )*ldg + j);
    float4 b = *(const float4*)(g + (size_t)(2*kp+1)*ldg + j);
    Ls[(j+0)*LDK + kp] = pack2h(a.x, b.x);
    Ls[(j+1)*LDK + kp] = pack2h(a.y, b.y);
    Ls[(j+2)*LDK + kp] = pack2h(a.z, b.z);
    Ls[(j+3)*LDK + kp] = pack2h(a.w, b.w);
  }
}
// one BK=64 chunk: wave w owns cols w*32..+31 (2 col-frags); 8 row-frags.
__device__ __forceinline__ void mfma_inner(const unsigned* As, const unsigned* Bs,
                                           f32x4 (&acc)[8][2], int w, int l){
  int lr = l & 15, lq = l >> 4;
  #pragma unroll
  for (int kt = 0; kt < 2; kt++){
    f16x8 bf0, bf1;
    {
      uint4 q0 = *(const uint4*)&Bs[(w*32 +      lr)*LDK + kt*16 + lq*4];
      uint4 q1 = *(const uint4*)&Bs[(w*32 + 16 + lr)*LDK + kt*16 + lq*4];
      bf0 = __builtin_bit_cast(f16x8, q0);
      bf1 = __builtin_bit_cast(f16x8, q1);
    }
    #pragma unroll
    for (int rf = 0; rf < 8; rf++){
      uint4 qa = *(const uint4*)&As[(rf*16 + lr)*LDK + kt*16 + lq*4];
      f16x8 af = __builtin_bit_cast(f16x8, qa);
      acc[rf][0] = __builtin_amdgcn_mfma_f32_16x16x32_f16(af, bf0, acc[rf][0], 0,0,0);
      acc[rf][1] = __builtin_amdgcn_mfma_f32_16x16x32_f16(af, bf1, acc[rf][1], 0,0,0);
    }
  }
}

// ---------------- K1: HQ' = SC*(P@wq^T+bq) ; PP' = SC*(P@wp^T+bp) --------
__global__ __launch_bounds__(256) void k1_hq_pp(
    const float* __restrict__ P,
    const float* __restrict__ wq_w, const float* __restrict__ wq_b,
    const float* __restrict__ wp_w, const float* __restrict__ wp_b,
    float* __restrict__ HQ, float* __restrict__ PP)
{
  __shared__ __align__(16) float Xs[64*132];
  __shared__ __align__(16) float Ws[64*132];
  int rt = blockIdx.x, ct = blockIdx.y;
  const float* W  = (ct < 2) ? wq_w : wp_w;
  const float* Bv = (ct < 2) ? wq_b : wp_b;
  float* O = (ct < 2) ? HQ : PP;
  int c0 = (ct & 1) * 128, r0 = rt * 128;
  int tid = threadIdx.x, rg = tid & 15, cg = tid >> 4;
  float acc[8][8];
  #pragma unroll
  for (int i=0;i<8;i++)
    #pragma unroll
    for (int j=0;j<8;j++) acc[i][j]=0.f;
  for (int kc = 0; kc < 4; kc++){
    __syncthreads();
    stage_t128(Xs, P + (size_t)r0*HH + kc*64, HH);
    stage_t128(Ws, W + (size_t)c0*HH + kc*64, HH);
    __syncthreads();
    rg_inner128(Xs, Ws, acc, rg, cg);
  }
  float bj[8];
  #pragma unroll
  for (int j=0;j<8;j++) bj[j] = Bv[c0 + COL_OF(j,cg)];
  #pragma unroll
  for (int i=0;i<8;i++){
    int r = r0 + ROW_OF(i,rg);
    #pragma unroll
    for (int j=0;j<8;j++)
      O[(size_t)r*HH + c0 + COL_OF(j,cg)] = SCALE_K2 * (acc[i][j] + bj[j]);
  }
}

// ---------------- K2: S_eff[b,t,l] = -2 * sum_h w_h / (1 + exp2(HQ'+PP')) -
__global__ __launch_bounds__(256) void k2_scores(
    const float* __restrict__ HQ, const float* __restrict__ PP,
    const float* __restrict__ ws_w, float* __restrict__ S)
{
  __shared__ float Hq_c[128*65];
  __shared__ float Pp_c[32*65];
  __shared__ float wsl[256];
  int tid = threadIdx.x;
  int b = blockIdx.y, t0 = blockIdx.x * 32;
  wsl[tid] = ws_w[tid];
  int tg = tid >> 6;
  int lg = tid & 63;
  for (int lc = 0; lc < 4; lc++){
    float acc[8][2];
    #pragma unroll
    for (int i=0;i<8;i++){ acc[i][0]=0.f; acc[i][1]=0.f; }
    for (int hc = 0; hc < 4; hc++){
      __syncthreads();
      {
        int r = tid >> 4, kq = (tid & 15) * 4;
        #pragma unroll
        for (int it=0; it<2; it++){
          int t = r + 16*it;
          float4 v = *(const float4*)(PP + ((size_t)b*LL + t0 + t)*HH + hc*64 + kq);
          float* d = Pp_c + t*65 + kq;
          d[0]=v.x; d[1]=v.y; d[2]=v.z; d[3]=v.w;
        }
      }
      {
        int r = tid >> 4, kq = (tid & 15) * 4;
        #pragma unroll
        for (int it=0; it<8; it++){
          int l = r + 16*it;
          float4 v = *(const float4*)(HQ + ((size_t)b*LL + lc*128 + l)*HH + hc*64 + kq);
          float* d = Hq_c + l*65 + kq;
          d[0]=v.x; d[1]=v.y; d[2]=v.z; d[3]=v.w;
        }
      }
      __syncthreads();
      #pragma unroll 2
      for (int h = 0; h < 64; h++){
        float w = wsl[hc*64 + h];
        float pp[8], hq[2];
        #pragma unroll
        for (int i=0;i<8;i++) pp[i] = Pp_c[(tg + 4*i)*65 + h];
        #pragma unroll
        for (int j=0;j<2;j++) hq[j] = Hq_c[(2*lg + j)*65 + h];
        #pragma unroll
        for (int i=0;i<8;i++)
          #pragma unroll
          for (int j=0;j<2;j++){
            float e = exp2f_fast(pp[i] + hq[j]);
            acc[i][j] = fmaf(w, rcpf_fast(1.0f + e), acc[i][j]);
          }
      }
    }
    #pragma unroll
    for (int i=0;i<8;i++)
      #pragma unroll
      for (int j=0;j<2;j++)
        S[((size_t)b*LL + t0 + tg + 4*i)*LL + lc*128 + 2*lg + j] = -2.0f*acc[i][j];
    __syncthreads();
  }
}

// ---------------- K3: softmax over l, in place; one wave per row ----------
__global__ __launch_bounds__(256) void k3_softmax(float* __restrict__ S)
{
  int wave = threadIdx.x >> 6, lane = threadIdx.x & 63;
  size_t row = (size_t)blockIdx.x*4 + wave;
  float* p = S + row*LL;
  float v[8];
  #pragma unroll
  for (int i=0;i<8;i++) v[i] = p[lane + 64*i];
  float m = v[0];
  #pragma unroll
  for (int i=1;i<8;i++) m = fmaxf(m, v[i]);
  #pragma unroll
  for (int off=32; off>=1; off>>=1) m = fmaxf(m, __shfl_xor(m, off, 64));
  float s = 0.f;
  #pragma unroll
  for (int i=0;i<8;i++){ v[i] = exp2f_fast((v[i]-m)*1.4426950408889634f); s += v[i]; }
  #pragma unroll
  for (int off=32; off>=1; off>>=1) s += __shfl_xor(s, off, 64);
  float inv = 1.0f / s;
  #pragma unroll
  for (int i=0;i<8;i++) p[lane + 64*i] = v[i]*inv;
}

// ---------------- K4: C[b,t,:] = attn[b,t,:] @ P[b,:,:] (MFMA) ------------
// grid (2 jt, 4 tt, 32 b); K = l = 512 in 8 chunks of 64.
__global__ __launch_bounds__(256, 4) void k4_context(
    const float* __restrict__ S, const float* __restrict__ P, float* __restrict__ C)
{
  __shared__ __align__(16) unsigned As[128*LDK];
  __shared__ __align__(16) unsigned Bs[128*LDK];
  int j0 = blockIdx.x * 128, t0 = blockIdx.y * 128, b = blockIdx.z;
  int tid = threadIdx.x, w = tid >> 6, l = tid & 63;
  f32x4 acc[8][2];
  #pragma unroll
  for (int i=0;i<8;i++){ acc[i][0]=(f32x4){0,0,0,0}; acc[i][1]=(f32x4){0,0,0,0}; }
  for (int lc = 0; lc < 8; lc++){
    int l0 = lc*64;
    __syncthreads();
    mstage_direct(As, S + ((size_t)b*LL + t0)*LL + l0, LL);     // A[t][l]
    mstage_trans (Bs, P + ((size_t)b*LL + l0)*HH + j0, HH);     // B[l][j] -> [j][lp]
    __syncthreads();
    mfma_inner(As, Bs, acc, w, l);
  }
  int lr = l & 15, lq = l >> 4;
  #pragma unroll
  for (int rf=0; rf<8; rf++)
    #pragma unroll
    for (int cf=0; cf<2; cf++){
      int col = j0 + w*32 + cf*16 + lr;
      #pragma unroll
      for (int r=0; r<4; r++){
        int row = t0 + rf*16 + lq*4 + r;
        C[((size_t)b*LL + row)*HH + col] = acc[rf][cf][r];
      }
    }
}

// ---------------- K5: Cg = sigmoid([P|C]@wg^T + bg) * C (MFMA) ------------
// grid (128 row-tiles, 2 col-tiles); K = 512 (P then C), 8 chunks.
__global__ __launch_bounds__(256, 4) void k5_gate(
    const float* __restrict__ P, const float* __restrict__ C,
    const float* __restrict__ wg_w, const float* __restrict__ wg_b,
    float* __restrict__ CG)
{
  __shared__ __align__(16) unsigned As[128*LDK];
  __shared__ __align__(16) unsigned Bs[128*LDK];
  int r0 = blockIdx.x*128, c0 = blockIdx.y*128;
  int tid = threadIdx.x, w = tid >> 6, l = tid & 63;
  f32x4 acc[8][2];
  #pragma unroll
  for (int i=0;i<8;i++){ acc[i][0]=(f32x4){0,0,0,0}; acc[i][1]=(f32x4){0,0,0,0}; }
  for (int kc = 0; kc < 8; kc++){
    const float* Xsrc = (kc < 4) ? (P + (size_t)r0*HH + kc*64)
                                 : (C + (size_t)r0*HH + (kc-4)*64);
    __syncthreads();
    mstage_direct(As, Xsrc, HH);
    mstage_direct(Bs, wg_w + (size_t)c0*(2*HH) + kc*64, 2*HH);  // B[c][k]
    __syncthreads();
    mfma_inner(As, Bs, acc, w, l);
  }
  int lr = l & 15, lq = l >> 4;
  #pragma unroll
  for (int cf=0; cf<2; cf++){
    int col = c0 + w*32 + cf*16 + lr;
    float bj = wg_b[col];
    #pragma unroll
    for (int rf=0; rf<8; rf++)
      #pragma unroll
      for (int r=0; r<4; r++){
        int row = r0 + rf*16 + lq*4 + r;
        float g = sigmoid_fast(acc[rf][cf][r] + bj);
        CG[(size_t)row*HH + col] = g * C[(size_t)row*HH + col];
      }
  }
}

// ---------------- K6: GI_{l,r} = Cg @ Wih^T + bih (MFMA) ------------------
// grid (128 row-tiles, 12 col-tiles): ct<6 left, else right; K=256, 4 chunks.
__global__ __launch_bounds__(256, 4) void k6_gi(
    const float* __restrict__ CG,
    const float* __restrict__ Wih_l, const float* __restrict__ bih_l,
    const float* __restrict__ Wih_r, const float* __restrict__ bih_r,
    float* __restrict__ GIL, float* __restrict__ GIR)
{
  __shared__ __align__(16) unsigned As[128*LDK];
  __shared__ __align__(16) unsigned Bs[128*LDK];
  int rt = blockIdx.x, ct = blockIdx.y;
  int dir = (ct >= 6);
  const float* Wih = dir ? Wih_r : Wih_l;
  const float* bih = dir ? bih_r : bih_l;
  float* GI = dir ? GIR : GIL;
  int c0 = (ct % 6) * 128, r0 = rt * 128;
  int tid = threadIdx.x, w = tid >> 6, l = tid & 63;
  f32x4 acc[8][2];
  #pragma unroll
  for (int i=0;i<8;i++){ acc[i][0]=(f32x4){0,0,0,0}; acc[i][1]=(f32x4){0,0,0,0}; }
  for (int kc = 0; kc < 4; kc++){
    __syncthreads();
    mstage_direct(As, CG  + (size_t)r0*HH + kc*64, HH);
    mstage_direct(Bs, Wih + (size_t)c0*HH + kc*64, HH);
    __syncthreads();
    mfma_inner(As, Bs, acc, w, l);
  }
  int lr = l & 15, lq = l >> 4;
  #pragma unroll
  for (int cf=0; cf<2; cf++){
    int col = c0 + w*32 + cf*16 + lr;
    float bj = bih[col];
    #pragma unroll
    for (int rf=0; rf<8; rf++)
      #pragma unroll
      for (int r=0; r<4; r++){
        int row = r0 + rf*16 + lq*4 + r;
        GI[(size_t)row*768 + col] = acc[rf][cf][r] + bj;
      }
  }
}

// ---------------- K7: GRU scans (R8 = R6 + pacing; measured 645us) --------
// 64 blocks (b,dir) x 512 threads. Thread t: u = t>>1, ks = t&1 (k half).
// Gate rows {u,u+256,u+512} over k in [ks*128, +128): 64 u32 weights/gate,
// 192 total. Pacing: staging 3 rounds x 4 float4; h-reads 4 sub-chunks x
// 4 uint4; weight preload 8 rounds x (3x8 float2). One barrier per step.
__global__ __launch_bounds__(512, 2) void k7_scan(
    const float* __restrict__ GIL, const float* __restrict__ GIR,
    const float* __restrict__ Whh_l, const float* __restrict__ bhh_l,
    const float* __restrict__ Whh_r, const float* __restrict__ bhh_r,
    float* __restrict__ out)
{
  int b   = blockIdx.x >> 1;
  int dir = blockIdx.x & 1;
  int t   = threadIdx.x;
  int u   = t >> 1;          // output dim 0..255
  int ks  = t & 1;           // k half
  int k0  = ks * 128;
  const float* GI  = dir ? GIR : GIL;
  const float* Whh = dir ? Whh_r : Whh_l;
  const float* bhh = dir ? bhh_r : bhh_l;

  unsigned w_r[64], w_z[64], w_n[64];
  {
    const float2* wr = (const float2*)(Whh + (size_t)(u      )*HH + k0);
    const float2* wz = (const float2*)(Whh + (size_t)(u + 256)*HH + k0);
    const float2* wn = (const float2*)(Whh + (size_t)(u + 512)*HH + k0);
    #pragma unroll
    for (int pc = 0; pc < 8; pc++){
      #pragma unroll
      for (int p = pc*8; p < pc*8+8; p++){ float2 a = wr[p]; w_r[p] = pack2h(a.x, a.y); }
      __builtin_amdgcn_sched_barrier(0);
      #pragma unroll
      for (int p = pc*8; p < pc*8+8; p++){ float2 a = wz[p]; w_z[p] = pack2h(a.x, a.y); }
      __builtin_amdgcn_sched_barrier(0);
      #pragma unroll
      for (int p = pc*8; p < pc*8+8; p++){ float2 a = wn[p]; w_n[p] = pack2h(a.x, a.y); }
      __builtin_amdgcn_sched_barrier(0);
    }
  }
  float b_r = bhh[u], b_z = bhh[u + 256], b_n = bhh[u + 512];

  __shared__ __align__(16) unsigned hsbuf[2][128];   // fp16 h, ping-pong
  __shared__ __align__(16) float gi_buf[32*768];     // 96 KB
  __shared__ __align__(16) float out_buf[32*256];    // 32 KB
  if (t < 128){ hsbuf[0][t] = 0; }

  float hprev = 0.f;

  #pragma unroll 1
  for (int chunk = 0; chunk < 16; chunk++){
    int s0 = chunk * 32;
    int tlo = dir ? (LL - s0 - 32) : s0;    // staged t range [tlo, tlo+31]
    {
      const float4* src = (const float4*)(GI + ((size_t)b*LL + tlo)*768);
      float4* dst = (float4*)gi_buf;
      #pragma unroll
      for (int rd = 0; rd < 3; rd++){
        float4 v0 = src[t + 512*(4*rd+0)];
        float4 v1 = src[t + 512*(4*rd+1)];
        float4 v2 = src[t + 512*(4*rd+2)];
        float4 v3 = src[t + 512*(4*rd+3)];
        dst[t + 512*(4*rd+0)] = v0;
        dst[t + 512*(4*rd+1)] = v1;
        dst[t + 512*(4*rd+2)] = v2;
        dst[t + 512*(4*rd+3)] = v3;
        __builtin_amdgcn_sched_barrier(0);
      }
    }
    __syncthreads();   // gi_buf ready; hs writes from prev step visible

    #pragma unroll 1
    for (int p = 0; p < 32; p++){
      int s = s0 + p;
      int tt = dir ? (LL-1-s) : s;
      int gidx = tt - tlo;                  // 0..31
      float ar0=0.f, ar1=0.f, az0=0.f, az1=0.f, an0=0.f, an1=0.f;
      #pragma unroll
      for (int sc = 0; sc < 4; sc++){
        const uint4* hp = (const uint4*)(hsbuf[s & 1]) + ks*16 + sc*4;
        uint4 q0 = hp[0], q1 = hp[1], q2 = hp[2], q3 = hp[3];
        unsigned hv[16] = {q0.x,q0.y,q0.z,q0.w, q1.x,q1.y,q1.z,q1.w,
                           q2.x,q2.y,q2.z,q2.w, q3.x,q3.y,q3.z,q3.w};
        #pragma unroll
        for (int j = 0; j < 16; j += 2){
          int pp = sc*16 + j;
          ar0 = dot2_acc(w_r[pp  ], hv[j  ], ar0);
          az0 = dot2_acc(w_z[pp  ], hv[j  ], az0);
          an0 = dot2_acc(w_n[pp  ], hv[j  ], an0);
          ar1 = dot2_acc(w_r[pp+1], hv[j+1], ar1);
          az1 = dot2_acc(w_z[pp+1], hv[j+1], az1);
          an1 = dot2_acc(w_n[pp+1], hv[j+1], an1);
        }
        __builtin_amdgcn_sched_barrier(0);
      }
      float ar = ar0 + ar1, az = az0 + az1, an = an0 + an1;
      ar += __shfl_xor(ar, 1, 64);
      az += __shfl_xor(az, 1, 64);
      an += __shfl_xor(an, 1, 64);
      const float* g = gi_buf + (size_t)gidx*768;
      float r  = sigmoid_fast(g[u      ] + ar + b_r);
      float z  = sigmoid_fast(g[u + 256] + az + b_z);
      float n  = tanh_fast  (g[u + 512] + r*(an + b_n));
      float hn = z*(hprev - n) + n;
      hprev = hn;
      if (ks == 0){
        out_buf[p*256 + u] = hn;
        ((unsigned short*)hsbuf[(s & 1) ^ 1])[u] =
            __builtin_bit_cast(unsigned short, (_Float16)hn);
      }
      __syncthreads();   // hs(write-buf) ready; separates reads from next writes
    }
    #pragma unroll
    for (int fr = 0; fr < 4; fr++){
      #pragma unroll
      for (int q = 0; q < 4; q++){
        int i = t + 512*(fr*4 + q);
        int p = i >> 8, uu = i & 255;
        int s = s0 + p;
        int tt = dir ? (LL-1-s) : s;
        out[((size_t)b*LL + tt)*(2*HH) + dir*HH + uu] = out_buf[i];
      }
      __builtin_amdgcn_sched_barrier(0);
    }
    __syncthreads();   // out_buf/gi_buf safe to reuse
  }
}

extern "C" void kernel_launch(void* const* d_in, const int* in_sizes, int n_in,
                              void* d_out, int out_size, void* d_ws, size_t ws_size,
                              hipStream_t stream)
{
  const float* P    = (const float*)d_in[0];
  const float* wq_w = (const float*)d_in[1];
  const float* wq_b = (const float*)d_in[2];
  const float* wp_w = (const float*)d_in[3];
  const float* wp_b = (const float*)d_in[4];
  const float* ws_w = (const float*)d_in[5];
  // d_in[6] = ws_b: softmax-invariant, unused
  const float* wg_w = (const float*)d_in[7];
  const float* wg_b = (const float*)d_in[8];
  const float* Wih_l= (const float*)d_in[9];
  const float* Whh_l= (const float*)d_in[10];
  const float* bih_l= (const float*)d_in[11];
  const float* bhh_l= (const float*)d_in[12];
  const float* Wih_r= (const float*)d_in[13];
  const float* Whh_r= (const float*)d_in[14];
  const float* bih_r= (const float*)d_in[15];
  const float* bhh_r= (const float*)d_in[16];

  float* ws  = (float*)d_ws;
  float* HQ  = ws;                    //  4,194,304
  float* PP  = ws + 4194304;          //  4,194,304
  float* S   = ws + 8388608;          //  8,388,608
  float* C   = ws + 16777216;         //  4,194,304
  float* CG  = ws + 20971520;         //  4,194,304
  float* GIR = ws + 25165824;         // 12,582,912
  float* GIL = ws;                    // 12,582,912 (aliases HQ/PP/S-front; dead by k6)
  float* out = (float*)d_out;

  k1_hq_pp  <<<dim3(128, 4),    256, 0, stream>>>(P, wq_w, wq_b, wp_w, wp_b, HQ, PP);
  k2_scores <<<dim3(16, 32),    256, 0, stream>>>(HQ, PP, ws_w, S);
  k3_softmax<<<4096,            256, 0, stream>>>(S);
  k4_context<<<dim3(2, 4, 32),  256, 0, stream>>>(S, P, C);
  k5_gate   <<<dim3(128, 2),    256, 0, stream>>>(P, C, wg_w, wg_b, CG);
  k6_gi     <<<dim3(128, 12),   256, 0, stream>>>(CG, Wih_l, bih_l, Wih_r, bih_r, GIL, GIR);
  k7_scan   <<<64,              512, 0, stream>>>(GIL, GIR, Whh_l, bhh_l, Whh_r, bhh_r, out);
}

// Round 18
// 1169.871 us; speedup vs baseline: 2.4808x; 1.1400x over previous
//
#include <hip/hip_runtime.h>
#include <cstdint>

// SelfMatchingLayer: B=32, L=512, H=256, fp32.
// R13: score-path optimization (k1/k2/k3; k4-k7 = R12 measured 1333.7us).
//      (a) exp2-hoisting: k1 now stores EH = exp2(SC*(P@w^T+b)) (O(LH)
//      exp2s); k2's inner e = exp2(hq'+pp') becomes e = hq_e*pp_e (1 mul)
//      -- exact by exp2(a+b)=exp2(a)exp2(b); trans ops/h-iter halve
//      (32->16, the dominant issue term). Range |SC*x|<~17 -> e<=1.6e5,
//      product <=2.7e10, fp32-safe. (b) k3 softmax FUSED into k2: block
//      already holds all 512 l-cols for its 32 rows as acc4[4][8][2]
//      (wave tg owns rows tg+4i = k3's exact mapping) -> in-register wave
//      softmax; k3's 67MB round-trip + dispatch deleted. lc loop fully
//      unrolled (static acc4 indexing).

#define LL 512
#define HH 256

typedef _Float16 half2_t __attribute__((ext_vector_type(2)));
typedef _Float16 f16x8   __attribute__((ext_vector_type(8)));
typedef float    f32x4   __attribute__((ext_vector_type(4)));

__device__ __forceinline__ float exp2f_fast(float x){
#if defined(__HIP_DEVICE_COMPILE__)
  return __builtin_amdgcn_exp2f(x);
#else
  return exp2f(x);
#endif
}
__device__ __forceinline__ float rcpf_fast(float x){
#if defined(__HIP_DEVICE_COMPILE__)
  return __builtin_amdgcn_rcpf(x);
#else
  return 1.0f/x;
#endif
}
__device__ __forceinline__ float tanh_fast(float x){
  float e = exp2f_fast(x * 2.885390081777927f);   // 2*log2(e)
  return 1.0f - 2.0f * rcpf_fast(1.0f + e);
}
__device__ __forceinline__ float sigmoid_fast(float x){
  return rcpf_fast(1.0f + exp2f_fast(x * -1.4426950408889634f));
}

#define SCALE_K2 2.885390081777927f   // 2*log2(e)

#if defined(__HIP_DEVICE_COMPILE__) && __has_builtin(__builtin_amdgcn_fdot2)
#define USE_FDOT2 1
#endif

__device__ __forceinline__ float dot2_acc(unsigned wb, unsigned hb, float a){
  half2_t wv = __builtin_bit_cast(half2_t, wb);
  half2_t hv = __builtin_bit_cast(half2_t, hb);
#ifdef USE_FDOT2
  return __builtin_amdgcn_fdot2(wv, hv, a, false);
#else
  return a + (float)wv.x*(float)hv.x + (float)wv.y*(float)hv.y;
#endif
}

__device__ __forceinline__ unsigned pack2h(float a, float b){
  half2_t h = { (_Float16)a, (_Float16)b };
  return __builtin_bit_cast(unsigned, h);
}

// ==== fp32 128x128-tile GEMM helpers (k1 only) ===========================
__device__ __forceinline__ void stage_t128(float* Ls, const float* g, int ldg){
  int tid = threadIdx.x;
  int r = tid >> 4, kq = (tid & 15) * 4;
  #pragma unroll
  for (int it = 0; it < 8; it++){
    int rr = r + 16*it;
    float4 v = *(const float4*)(g + (size_t)rr*ldg + kq);
    Ls[(kq+0)*132 + rr] = v.x;
    Ls[(kq+1)*132 + rr] = v.y;
    Ls[(kq+2)*132 + rr] = v.z;
    Ls[(kq+3)*132 + rr] = v.w;
  }
}
__device__ __forceinline__ void rg_inner128(const float* Xs, const float* Ws,
                                            float (&acc)[8][8], int rg, int cg){
  #pragma unroll 2
  for (int k = 0; k < 64; k++){
    const float* xr = Xs + k*132;
    const float* wr = Ws + k*132;
    float4 x0 = *(const float4*)(xr + rg*4);
    float4 x1 = *(const float4*)(xr + 64 + rg*4);
    float4 w0 = *(const float4*)(wr + cg*4);
    float4 w1 = *(const float4*)(wr + 64 + cg*4);
    float xv[8] = {x0.x,x0.y,x0.z,x0.w, x1.x,x1.y,x1.z,x1.w};
    float wv[8] = {w0.x,w0.y,w0.z,w0.w, w1.x,w1.y,w1.z,w1.w};
    #pragma unroll
    for (int i=0;i<8;i++)
      #pragma unroll
      for (int j=0;j<8;j++)
        acc[i][j] = fmaf(xv[i], wv[j], acc[i][j]);
  }
}
#define ROW_OF(i, rg) ((rg)*4 + ((i)&3) + ((i)>>2)*64)
#define COL_OF(j, cg) ((cg)*4 + ((j)&3) + ((j)>>2)*64)

// ==== MFMA 128x128-tile GEMM helpers (k4/k5/k6) ==========================
// LDS: [128 rows][LDK u32] k-pair layout; row stride 36 u32 = 144 B.
#define LDK 36

__device__ __forceinline__ void mstage_direct(unsigned* Ls, const float* g, int ldg){
  int tid = threadIdx.x;
  int row = tid >> 1, half = tid & 1;
  const float4* s = (const float4*)(g + (size_t)row*ldg + half*32);
  unsigned* d = Ls + row*LDK + half*16;
  #pragma unroll
  for (int i = 0; i < 8; i += 2){
    float4 a = s[i], b = s[i+1];
    uint4 o;
    o.x = pack2h(a.x,a.y); o.y = pack2h(a.z,a.w);
    o.z = pack2h(b.x,b.y); o.w = pack2h(b.z,b.w);
    *(uint4*)(d + i*2) = o;
  }
}
__device__ __forceinline__ void mstage_trans(unsigned* Ls, const float* g, int ldg){
  int tid = threadIdx.x;
  int j = (tid & 31) * 4, kq = tid >> 5;
  #pragma unroll
  for (int it = 0; it < 4; it++){
    int kp = kq*4 + it;
    float4 a = *(const float4*)(g + (size_t)(2*kp  )*ldg + j);
    float4 b = *(const float4*)(g + (size_t)(2*kp+1)*ldg + j);
    Ls[(j+0)*LDK + kp] = pack2h(a.x, b.x);
    Ls[(j+1)*LDK + kp] = pack2h(a.y, b.y);
    Ls[(j+2)*LDK + kp] = pack2h(a.z, b.z);
    Ls[(j+3)*LDK + kp] = pack2h(a.w, b.w);
  }
}
__device__ __forceinline__ void mfma_inner(const unsigned* As, const unsigned* Bs,
                                           f32x4 (&acc)[8][2], int w, int l){
  int lr = l & 15, lq = l >> 4;
  #pragma unroll
  for (int kt = 0; kt < 2; kt++){
    f16x8 bf0, bf1;
    {
      uint4 q0 = *(const uint4*)&Bs[(w*32 +      lr)*LDK + kt*16 + lq*4];
      uint4 q1 = *(const uint4*)&Bs[(w*32 + 16 + lr)*LDK + kt*16 + lq*4];
      bf0 = __builtin_bit_cast(f16x8, q0);
      bf1 = __builtin_bit_cast(f16x8, q1);
    }
    #pragma unroll
    for (int rf = 0; rf < 8; rf++){
      uint4 qa = *(const uint4*)&As[(rf*16 + lr)*LDK + kt*16 + lq*4];
      f16x8 af = __builtin_bit_cast(f16x8, qa);
      acc[rf][0] = __builtin_amdgcn_mfma_f32_16x16x32_f16(af, bf0, acc[rf][0], 0,0,0);
      acc[rf][1] = __builtin_amdgcn_mfma_f32_16x16x32_f16(af, bf1, acc[rf][1], 0,0,0);
    }
  }
}

// ---------------- K1: EH = exp2(SC*(P@wq^T+bq)) ; EP = exp2(SC*(P@wp^T+bp))
__global__ __launch_bounds__(256) void k1_hq_pp(
    const float* __restrict__ P,
    const float* __restrict__ wq_w, const float* __restrict__ wq_b,
    const float* __restrict__ wp_w, const float* __restrict__ wp_b,
    float* __restrict__ HQ, float* __restrict__ PP)
{
  __shared__ __align__(16) float Xs[64*132];
  __shared__ __align__(16) float Ws[64*132];
  int rt = blockIdx.x, ct = blockIdx.y;
  const float* W  = (ct < 2) ? wq_w : wp_w;
  const float* Bv = (ct < 2) ? wq_b : wp_b;
  float* O = (ct < 2) ? HQ : PP;
  int c0 = (ct & 1) * 128, r0 = rt * 128;
  int tid = threadIdx.x, rg = tid & 15, cg = tid >> 4;
  float acc[8][8];
  #pragma unroll
  for (int i=0;i<8;i++)
    #pragma unroll
    for (int j=0;j<8;j++) acc[i][j]=0.f;
  for (int kc = 0; kc < 4; kc++){
    __syncthreads();
    stage_t128(Xs, P + (size_t)r0*HH + kc*64, HH);
    stage_t128(Ws, W + (size_t)c0*HH + kc*64, HH);
    __syncthreads();
    rg_inner128(Xs, Ws, acc, rg, cg);
  }
  float bj[8];
  #pragma unroll
  for (int j=0;j<8;j++) bj[j] = Bv[c0 + COL_OF(j,cg)];
  #pragma unroll
  for (int i=0;i<8;i++){
    int r = r0 + ROW_OF(i,rg);
    #pragma unroll
    for (int j=0;j<8;j++)
      O[(size_t)r*HH + c0 + COL_OF(j,cg)] =
          exp2f_fast(SCALE_K2 * (acc[i][j] + bj[j]));
  }
}

// ---------------- K2: scores + FUSED softmax ------------------------------
// S_eff[b,t,l] = -2 * sum_h w_h / (1 + EH[b,l,h]*EP[b,t,h]); then softmax
// over l in-register (wave tg owns rows tg+4i; lane holds 8 cols).
__global__ __launch_bounds__(256) void k2_scores(
    const float* __restrict__ HQ, const float* __restrict__ PP,
    const float* __restrict__ ws_w, float* __restrict__ S)
{
  __shared__ float Hq_c[128*65];
  __shared__ float Pp_c[32*65];
  __shared__ float wsl[256];
  int tid = threadIdx.x;
  int b = blockIdx.y, t0 = blockIdx.x * 32;
  wsl[tid] = ws_w[tid];
  int tg = tid >> 6;
  int lg = tid & 63;
  float acc4[4][8][2];
  #pragma unroll
  for (int lc=0;lc<4;lc++)
    #pragma unroll
    for (int i=0;i<8;i++){ acc4[lc][i][0]=0.f; acc4[lc][i][1]=0.f; }
  #pragma unroll
  for (int lc = 0; lc < 4; lc++){
    #pragma unroll 1
    for (int hc = 0; hc < 4; hc++){
      __syncthreads();
      {
        int r = tid >> 4, kq = (tid & 15) * 4;
        #pragma unroll
        for (int it=0; it<2; it++){
          int t = r + 16*it;
          float4 v = *(const float4*)(PP + ((size_t)b*LL + t0 + t)*HH + hc*64 + kq);
          float* d = Pp_c + t*65 + kq;
          d[0]=v.x; d[1]=v.y; d[2]=v.z; d[3]=v.w;
        }
      }
      {
        int r = tid >> 4, kq = (tid & 15) * 4;
        #pragma unroll
        for (int it=0; it<8; it++){
          int l = r + 16*it;
          float4 v = *(const float4*)(HQ + ((size_t)b*LL + lc*128 + l)*HH + hc*64 + kq);
          float* d = Hq_c + l*65 + kq;
          d[0]=v.x; d[1]=v.y; d[2]=v.z; d[3]=v.w;
        }
      }
      __syncthreads();
      #pragma unroll 2
      for (int h = 0; h < 64; h++){
        float w = wsl[hc*64 + h];
        float pp[8], hq[2];
        #pragma unroll
        for (int i=0;i<8;i++) pp[i] = Pp_c[(tg + 4*i)*65 + h];
        #pragma unroll
        for (int j=0;j<2;j++) hq[j] = Hq_c[(2*lg + j)*65 + h];
        #pragma unroll
        for (int i=0;i<8;i++)
          #pragma unroll
          for (int j=0;j<2;j++){
            float e = pp[i] * hq[j];                 // exp2 pre-hoisted (k1)
            acc4[lc][i][j] = fmaf(w, rcpf_fast(1.0f + e), acc4[lc][i][j]);
          }
      }
    }
  }
  // fused softmax over l (512 cols of row t0+tg+4i live in wave tg)
  #pragma unroll
  for (int i=0;i<8;i++){
    float v[8];
    #pragma unroll
    for (int lc=0;lc<4;lc++){
      v[lc*2+0] = -2.0f*acc4[lc][i][0];
      v[lc*2+1] = -2.0f*acc4[lc][i][1];
    }
    float m = v[0];
    #pragma unroll
    for (int k=1;k<8;k++) m = fmaxf(m, v[k]);
    #pragma unroll
    for (int off=32; off>=1; off>>=1) m = fmaxf(m, __shfl_xor(m, off, 64));
    float s = 0.f;
    #pragma unroll
    for (int k=0;k<8;k++){ v[k] = exp2f_fast((v[k]-m)*1.4426950408889634f); s += v[k]; }
    #pragma unroll
    for (int off=32; off>=1; off>>=1) s += __shfl_xor(s, off, 64);
    float inv = 1.0f / s;
    size_t base = ((size_t)b*LL + t0 + tg + 4*i)*LL;
    #pragma unroll
    for (int lc=0;lc<4;lc++){
      S[base + lc*128 + 2*lg + 0] = v[lc*2+0]*inv;
      S[base + lc*128 + 2*lg + 1] = v[lc*2+1]*inv;
    }
  }
}

// ---------------- K4: C[b,t,:] = attn[b,t,:] @ P[b,:,:] (MFMA) ------------
__global__ __launch_bounds__(256, 4) void k4_context(
    const float* __restrict__ S, const float* __restrict__ P, float* __restrict__ C)
{
  __shared__ __align__(16) unsigned As[128*LDK];
  __shared__ __align__(16) unsigned Bs[128*LDK];
  int j0 = blockIdx.x * 128, t0 = blockIdx.y * 128, b = blockIdx.z;
  int tid = threadIdx.x, w = tid >> 6, l = tid & 63;
  f32x4 acc[8][2];
  #pragma unroll
  for (int i=0;i<8;i++){ acc[i][0]=(f32x4){0,0,0,0}; acc[i][1]=(f32x4){0,0,0,0}; }
  for (int lc = 0; lc < 8; lc++){
    int l0 = lc*64;
    __syncthreads();
    mstage_direct(As, S + ((size_t)b*LL + t0)*LL + l0, LL);
    mstage_trans (Bs, P + ((size_t)b*LL + l0)*HH + j0, HH);
    __syncthreads();
    mfma_inner(As, Bs, acc, w, l);
  }
  int lr = l & 15, lq = l >> 4;
  #pragma unroll
  for (int rf=0; rf<8; rf++)
    #pragma unroll
    for (int cf=0; cf<2; cf++){
      int col = j0 + w*32 + cf*16 + lr;
      #pragma unroll
      for (int r=0; r<4; r++){
        int row = t0 + rf*16 + lq*4 + r;
        C[((size_t)b*LL + row)*HH + col] = acc[rf][cf][r];
      }
    }
}

// ---------------- K5: Cg = sigmoid([P|C]@wg^T + bg) * C (MFMA) ------------
__global__ __launch_bounds__(256, 4) void k5_gate(
    const float* __restrict__ P, const float* __restrict__ C,
    const float* __restrict__ wg_w, const float* __restrict__ wg_b,
    float* __restrict__ CG)
{
  __shared__ __align__(16) unsigned As[128*LDK];
  __shared__ __align__(16) unsigned Bs[128*LDK];
  int r0 = blockIdx.x*128, c0 = blockIdx.y*128;
  int tid = threadIdx.x, w = tid >> 6, l = tid & 63;
  f32x4 acc[8][2];
  #pragma unroll
  for (int i=0;i<8;i++){ acc[i][0]=(f32x4){0,0,0,0}; acc[i][1]=(f32x4){0,0,0,0}; }
  for (int kc = 0; kc < 8; kc++){
    const float* Xsrc = (kc < 4) ? (P + (size_t)r0*HH + kc*64)
                                 : (C + (size_t)r0*HH + (kc-4)*64);
    __syncthreads();
    mstage_direct(As, Xsrc, HH);
    mstage_direct(Bs, wg_w + (size_t)c0*(2*HH) + kc*64, 2*HH);
    __syncthreads();
    mfma_inner(As, Bs, acc, w, l);
  }
  int lr = l & 15, lq = l >> 4;
  #pragma unroll
  for (int cf=0; cf<2; cf++){
    int col = c0 + w*32 + cf*16 + lr;
    float bj = wg_b[col];
    #pragma unroll
    for (int rf=0; rf<8; rf++)
      #pragma unroll
      for (int r=0; r<4; r++){
        int row = r0 + rf*16 + lq*4 + r;
        float g = sigmoid_fast(acc[rf][cf][r] + bj);
        CG[(size_t)row*HH + col] = g * C[(size_t)row*HH + col];
      }
  }
}

// ---------------- K6: GI_{l,r} = Cg @ Wih^T + bih (MFMA) ------------------
__global__ __launch_bounds__(256, 4) void k6_gi(
    const float* __restrict__ CG,
    const float* __restrict__ Wih_l, const float* __restrict__ bih_l,
    const float* __restrict__ Wih_r, const float* __restrict__ bih_r,
    float* __restrict__ GIL, float* __restrict__ GIR)
{
  __shared__ __align__(16) unsigned As[128*LDK];
  __shared__ __align__(16) unsigned Bs[128*LDK];
  int rt = blockIdx.x, ct = blockIdx.y;
  int dir = (ct >= 6);
  const float* Wih = dir ? Wih_r : Wih_l;
  const float* bih = dir ? bih_r : bih_l;
  float* GI = dir ? GIR : GIL;
  int c0 = (ct % 6) * 128, r0 = rt * 128;
  int tid = threadIdx.x, w = tid >> 6, l = tid & 63;
  f32x4 acc[8][2];
  #pragma unroll
  for (int i=0;i<8;i++){ acc[i][0]=(f32x4){0,0,0,0}; acc[i][1]=(f32x4){0,0,0,0}; }
  for (int kc = 0; kc < 4; kc++){
    __syncthreads();
    mstage_direct(As, CG  + (size_t)r0*HH + kc*64, HH);
    mstage_direct(Bs, Wih + (size_t)c0*HH + kc*64, HH);
    __syncthreads();
    mfma_inner(As, Bs, acc, w, l);
  }
  int lr = l & 15, lq = l >> 4;
  #pragma unroll
  for (int cf=0; cf<2; cf++){
    int col = c0 + w*32 + cf*16 + lr;
    float bj = bih[col];
    #pragma unroll
    for (int rf=0; rf<8; rf++)
      #pragma unroll
      for (int r=0; r<4; r++){
        int row = r0 + rf*16 + lq*4 + r;
        GI[(size_t)row*768 + col] = acc[rf][cf][r] + bj;
      }
  }
}

// ---------------- K7: GRU scans (R8 = R6 + pacing; measured 645us) --------
__global__ __launch_bounds__(512, 2) void k7_scan(
    const float* __restrict__ GIL, const float* __restrict__ GIR,
    const float* __restrict__ Whh_l, const float* __restrict__ bhh_l,
    const float* __restrict__ Whh_r, const float* __restrict__ bhh_r,
    float* __restrict__ out)
{
  int b   = blockIdx.x >> 1;
  int dir = blockIdx.x & 1;
  int t   = threadIdx.x;
  int u   = t >> 1;          // output dim 0..255
  int ks  = t & 1;           // k half
  int k0  = ks * 128;
  const float* GI  = dir ? GIR : GIL;
  const float* Whh = dir ? Whh_r : Whh_l;
  const float* bhh = dir ? bhh_r : bhh_l;

  unsigned w_r[64], w_z[64], w_n[64];
  {
    const float2* wr = (const float2*)(Whh + (size_t)(u      )*HH + k0);
    const float2* wz = (const float2*)(Whh + (size_t)(u + 256)*HH + k0);
    const float2* wn = (const float2*)(Whh + (size_t)(u + 512)*HH + k0);
    #pragma unroll
    for (int pc = 0; pc < 8; pc++){
      #pragma unroll
      for (int p = pc*8; p < pc*8+8; p++){ float2 a = wr[p]; w_r[p] = pack2h(a.x, a.y); }
      __builtin_amdgcn_sched_barrier(0);
      #pragma unroll
      for (int p = pc*8; p < pc*8+8; p++){ float2 a = wz[p]; w_z[p] = pack2h(a.x, a.y); }
      __builtin_amdgcn_sched_barrier(0);
      #pragma unroll
      for (int p = pc*8; p < pc*8+8; p++){ float2 a = wn[p]; w_n[p] = pack2h(a.x, a.y); }
      __builtin_amdgcn_sched_barrier(0);
    }
  }
  float b_r = bhh[u], b_z = bhh[u + 256], b_n = bhh[u + 512];

  __shared__ __align__(16) unsigned hsbuf[2][128];   // fp16 h, ping-pong
  __shared__ __align__(16) float gi_buf[32*768];     // 96 KB
  __shared__ __align__(16) float out_buf[32*256];    // 32 KB
  if (t < 128){ hsbuf[0][t] = 0; }

  float hprev = 0.f;

  #pragma unroll 1
  for (int chunk = 0; chunk < 16; chunk++){
    int s0 = chunk * 32;
    int tlo = dir ? (LL - s0 - 32) : s0;    // staged t range [tlo, tlo+31]
    {
      const float4* src = (const float4*)(GI + ((size_t)b*LL + tlo)*768);
      float4* dst = (float4*)gi_buf;
      #pragma unroll
      for (int rd = 0; rd < 3; rd++){
        float4 v0 = src[t + 512*(4*rd+0)];
        float4 v1 = src[t + 512*(4*rd+1)];
        float4 v2 = src[t + 512*(4*rd+2)];
        float4 v3 = src[t + 512*(4*rd+3)];
        dst[t + 512*(4*rd+0)] = v0;
        dst[t + 512*(4*rd+1)] = v1;
        dst[t + 512*(4*rd+2)] = v2;
        dst[t + 512*(4*rd+3)] = v3;
        __builtin_amdgcn_sched_barrier(0);
      }
    }
    __syncthreads();   // gi_buf ready; hs writes from prev step visible

    #pragma unroll 1
    for (int p = 0; p < 32; p++){
      int s = s0 + p;
      int tt = dir ? (LL-1-s) : s;
      int gidx = tt - tlo;                  // 0..31
      float ar0=0.f, ar1=0.f, az0=0.f, az1=0.f, an0=0.f, an1=0.f;
      #pragma unroll
      for (int sc = 0; sc < 4; sc++){
        const uint4* hp = (const uint4*)(hsbuf[s & 1]) + ks*16 + sc*4;
        uint4 q0 = hp[0], q1 = hp[1], q2 = hp[2], q3 = hp[3];
        unsigned hv[16] = {q0.x,q0.y,q0.z,q0.w, q1.x,q1.y,q1.z,q1.w,
                           q2.x,q2.y,q2.z,q2.w, q3.x,q3.y,q3.z,q3.w};
        #pragma unroll
        for (int j = 0; j < 16; j += 2){
          int pp = sc*16 + j;
          ar0 = dot2_acc(w_r[pp  ], hv[j  ], ar0);
          az0 = dot2_acc(w_z[pp  ], hv[j  ], az0);
          an0 = dot2_acc(w_n[pp  ], hv[j  ], an0);
          ar1 = dot2_acc(w_r[pp+1], hv[j+1], ar1);
          az1 = dot2_acc(w_z[pp+1], hv[j+1], az1);
          an1 = dot2_acc(w_n[pp+1], hv[j+1], an1);
        }
        __builtin_amdgcn_sched_barrier(0);
      }
      float ar = ar0 + ar1, az = az0 + az1, an = an0 + an1;
      ar += __shfl_xor(ar, 1, 64);
      az += __shfl_xor(az, 1, 64);
      an += __shfl_xor(an, 1, 64);
      const float* g = gi_buf + (size_t)gidx*768;
      float r  = sigmoid_fast(g[u      ] + ar + b_r);
      float z  = sigmoid_fast(g[u + 256] + az + b_z);
      float n  = tanh_fast  (g[u + 512] + r*(an + b_n));
      float hn = z*(hprev - n) + n;
      hprev = hn;
      if (ks == 0){
        out_buf[p*256 + u] = hn;
        ((unsigned short*)hsbuf[(s & 1) ^ 1])[u] =
            __builtin_bit_cast(unsigned short, (_Float16)hn);
      }
      __syncthreads();   // hs(write-buf) ready; separates reads from next writes
    }
    #pragma unroll
    for (int fr = 0; fr < 4; fr++){
      #pragma unroll
      for (int q = 0; q < 4; q++){
        int i = t + 512*(fr*4 + q);
        int p = i >> 8, uu = i & 255;
        int s = s0 + p;
        int tt = dir ? (LL-1-s) : s;
        out[((size_t)b*LL + tt)*(2*HH) + dir*HH + uu] = out_buf[i];
      }
      __builtin_amdgcn_sched_barrier(0);
    }
    __syncthreads();   // out_buf/gi_buf safe to reuse
  }
}

extern "C" void kernel_launch(void* const* d_in, const int* in_sizes, int n_in,
                              void* d_out, int out_size, void* d_ws, size_t ws_size,
                              hipStream_t stream)
{
  const float* P    = (const float*)d_in[0];
  const float* wq_w = (const float*)d_in[1];
  const float* wq_b = (const float*)d_in[2];
  const float* wp_w = (const float*)d_in[3];
  const float* wp_b = (const float*)d_in[4];
  const float* ws_w = (const float*)d_in[5];
  // d_in[6] = ws_b: softmax-invariant, unused
  const float* wg_w = (const float*)d_in[7];
  const float* wg_b = (const float*)d_in[8];
  const float* Wih_l= (const float*)d_in[9];
  const float* Whh_l= (const float*)d_in[10];
  const float* bih_l= (const float*)d_in[11];
  const float* bhh_l= (const float*)d_in[12];
  const float* Wih_r= (const float*)d_in[13];
  const float* Whh_r= (const float*)d_in[14];
  const float* bih_r= (const float*)d_in[15];
  const float* bhh_r= (const float*)d_in[16];

  float* ws  = (float*)d_ws;
  float* HQ  = ws;                    //  4,194,304
  float* PP  = ws + 4194304;          //  4,194,304
  float* S   = ws + 8388608;          //  8,388,608
  float* C   = ws + 16777216;         //  4,194,304
  float* CG  = ws + 20971520;         //  4,194,304
  float* GIR = ws + 25165824;         // 12,582,912
  float* GIL = ws;                    // 12,582,912 (aliases HQ/PP/S-front; dead by k6)
  float* out = (float*)d_out;

  k1_hq_pp  <<<dim3(128, 4),    256, 0, stream>>>(P, wq_w, wq_b, wp_w, wp_b, HQ, PP);
  k2_scores <<<dim3(16, 32),    256, 0, stream>>>(HQ, PP, ws_w, S);
  k4_context<<<dim3(2, 4, 32),  256, 0, stream>>>(S, P, C);
  k5_gate   <<<dim3(128, 2),    256, 0, stream>>>(P, C, wg_w, wg_b, CG);
  k6_gi     <<<dim3(128, 12),   256, 0, stream>>>(CG, Wih_l, bih_l, Wih_r, bih_r, GIL, GIR);
  k7_scan   <<<64,              512, 0, stream>>>(GIL, GIR, Whh_l, bhh_l, Whh_r, bhh_r, out);
}